// Round 2
// 744.074 us; speedup vs baseline: 1.0575x; 1.0575x over previous
//
#include <hip/hip_runtime.h>
#include <hip/hip_bf16.h>
#include <cmath>

typedef __hip_bfloat16 bf16;
typedef float v4f __attribute__((ext_vector_type(4)));
typedef short v8s __attribute__((ext_vector_type(8)));   // 8 x bf16 bits
typedef short v4s __attribute__((ext_vector_type(4)));   // 4 x bf16 bits

__device__ __forceinline__ void load_lds16(const void* g, void* l) {
  __builtin_amdgcn_global_load_lds(
      (const __attribute__((address_space(1))) char*)g,
      (__attribute__((address_space(3))) char*)l, 16, 0, 0);
}
__device__ __forceinline__ v4f mfma16x16x32(v8s a, v8s b, v4f c) {
  return __builtin_amdgcn_mfma_f32_16x16x32_bf16(a, b, c, 0, 0, 0);
}
__device__ __forceinline__ v4f mfma16x16x16(v4s a, v4s b, v4f c) {
#if __has_builtin(__builtin_amdgcn_mfma_f32_16x16x16_bf16)
  return __builtin_amdgcn_mfma_f32_16x16x16_bf16(a, b, c, 0, 0, 0);
#elif __has_builtin(__builtin_amdgcn_mfma_f32_16x16x16bf16_1k)
  return __builtin_amdgcn_mfma_f32_16x16x16bf16_1k(a, b, c, 0, 0, 0);
#else
  v4f d;
  asm("v_mfma_f32_16x16x16_bf16 %0, %1, %2, %3"
      : "=v"(d) : "v"(a), "v"(b), "v"(c));
  return d;
#endif
}
__device__ __forceinline__ float b2f(bf16 x) { return __bfloat162float(x); }
__device__ __forceinline__ bf16 f2b(float x) { return __float2bfloat16(x); }
__device__ __forceinline__ ushort b2u(float x) {
  bf16 h = f2b(x);
  return *(ushort*)&h;
}
__device__ __forceinline__ float fexp2(float x) {
#if __has_builtin(__builtin_amdgcn_exp2f)
  return __builtin_amdgcn_exp2f(x);
#else
  return exp2f(x);
#endif
}
__device__ __forceinline__ float gelu_exact(float x) {
  return 0.5f * x * (1.0f + erff(x * 0.70710678118654752f));
}
__device__ __forceinline__ float finz(float v, float sent) {
  return __builtin_isfinite(v) ? v : sent;
}
__device__ __forceinline__ float u2f(ushort u) {
  return __uint_as_float(((unsigned)u) << 16);
}
__device__ __forceinline__ float4 load4f(const float* p) {
  return *(const float4*)p;
}
__device__ __forceinline__ float4 load4f(const bf16* p) {
  ushort4 u = *(const ushort4*)p;
  return make_float4(u2f(u.x), u2f(u.y), u2f(u.z), u2f(u.w));
}

// ---------------------------------------------------------------------------
// LayerNorm: one block per row of 1024, fp32 stats, bf16 out.
// ---------------------------------------------------------------------------
template <typename TI>
__global__ __launch_bounds__(256)
void ln_kernel(const TI* __restrict__ x, const float* __restrict__ g,
               const float* __restrict__ b, bf16* __restrict__ out) {
  __shared__ float red[8];
  __shared__ float stat[2];
  const int row = blockIdx.x, t = threadIdx.x;
  const int wave = t >> 6, lane = t & 63;
  float4 v = load4f(x + (long)row * 1024 + t * 4);
  float s = v.x + v.y + v.z + v.w;
  float s2 = v.x * v.x + v.y * v.y + v.z * v.z + v.w * v.w;
#pragma unroll
  for (int off = 32; off > 0; off >>= 1) {
    s += __shfl_down(s, off);
    s2 += __shfl_down(s2, off);
  }
  if (lane == 0) { red[wave * 2] = s; red[wave * 2 + 1] = s2; }
  __syncthreads();
  if (t == 0) {
    float S = red[0] + red[2] + red[4] + red[6];
    float S2 = red[1] + red[3] + red[5] + red[7];
    float mean = S * (1.0f / 1024.0f);
    float var = S2 * (1.0f / 1024.0f) - mean * mean;
    stat[0] = mean;
    stat[1] = rsqrtf(var + 1e-5f);
  }
  __syncthreads();
  const float mean = stat[0], rs = stat[1];
  bf16* orow = out + (long)row * 1024;
  const int c = t * 4;
  float4 gg = *(const float4*)(g + c);
  float4 bb = *(const float4*)(b + c);
  orow[c + 0] = f2b(finz((v.x - mean) * rs * gg.x + bb.x, 3000.f));
  orow[c + 1] = f2b(finz((v.y - mean) * rs * gg.y + bb.y, 3000.f));
  orow[c + 2] = f2b(finz((v.z - mean) * rs * gg.z + bb.z, 3000.f));
  orow[c + 3] = f2b(finz((v.w - mean) * rs * gg.w + bb.w, 3000.f));
}

// ---------------------------------------------------------------------------
// Repack Wq/Wk/Wv fp32 [H=16, D=1024, HD=64] -> bf16 Wt[n=h*64+kk][d]
// ---------------------------------------------------------------------------
__global__ __launch_bounds__(256)
void repack_qkv(const float* __restrict__ w, bf16* __restrict__ wt) {
  long i = (long)blockIdx.x * 256 + threadIdx.x;
  int n = (int)(i >> 10), d = (int)(i & 1023);
  int h = n >> 6, kk = n & 63;
  wt[i] = f2b(w[((long)h * 1024 + d) * 64 + kk]);
}

// ---------------------------------------------------------------------------
// Tiled transpose fp32 -> bf16: out[c*R + r] = in[r*C + c]
// ---------------------------------------------------------------------------
__global__ __launch_bounds__(256)
void transpose_f2b(const float* __restrict__ in, bf16* __restrict__ out,
                   int R, int C) {
  __shared__ float tile[32][33];
  const int tx = threadIdx.x & 31, ty = threadIdx.x >> 5;
  const int r0 = blockIdx.y * 32, c0 = blockIdx.x * 32;
#pragma unroll
  for (int i = ty; i < 32; i += 8) tile[i][tx] = in[(long)(r0 + i) * C + c0 + tx];
  __syncthreads();
#pragma unroll
  for (int i = ty; i < 32; i += 8)
    out[(long)(c0 + i) * R + r0 + tx] = f2b(tile[tx][i]);
}

// ---------------------------------------------------------------------------
// GEMM C[M,N] = A[M,K] @ Bt[N,K]^T (128x128, BK=32, async global_load_lds).
// EPI: 0=+bias (bf16)  1=+bias+fp32 resid (bf16)  2=gelu+bf16 resid (FP32)
//      3=QKV scatter: q (PRE-SCALED by 0.125*log2e), k -> [B,H,S,64];
//        v -> TRANSPOSED [B,H,64,S]
// ---------------------------------------------------------------------------
template <int EPI>
__global__ __launch_bounds__(256)
void gemm_bt(const bf16* __restrict__ A, const bf16* __restrict__ Bt,
             const float* __restrict__ bias0, const float* __restrict__ bias1,
             const float* __restrict__ bias2, const void* __restrict__ residv,
             void* __restrict__ C0v, bf16* __restrict__ C1, bf16* __restrict__ C2v,
             int M, int N, int K) {
  __shared__ bf16 As[128 * 32];
  __shared__ bf16 Bs[128 * 32];
  const int t = threadIdx.x;
  const int wave = t >> 6, lane = t & 63, quad = lane >> 4, ln = lane & 15;
  const int m0 = blockIdx.y * 128, n0 = blockIdx.x * 128;
  const int wm = (wave >> 1) * 64, wn = (wave & 1) * 64;

  v4f acc[4][4];
#pragma unroll
  for (int i = 0; i < 4; i++)
#pragma unroll
    for (int j = 0; j < 4; j++) acc[i][j] = v4f{0.f, 0.f, 0.f, 0.f};

  const int e0 = t * 8, e1 = t * 8 + 2048;
  const int ra0 = e0 >> 5, ca0 = e0 & 31, ra1 = e1 >> 5, ca1 = e1 & 31;
  const bf16* Ab = A + (long)m0 * K;
  const bf16* Bb = Bt + (long)n0 * K;

  for (int k0 = 0; k0 < K; k0 += 32) {
    __syncthreads();
    load_lds16(Ab + (long)ra0 * K + k0 + ca0, &As[e0]);
    load_lds16(Ab + (long)ra1 * K + k0 + ca1, &As[e1]);
    load_lds16(Bb + (long)ra0 * K + k0 + ca0, &Bs[e0]);
    load_lds16(Bb + (long)ra1 * K + k0 + ca1, &Bs[e1]);
    __syncthreads();
    v8s af[4], bfr[4];
#pragma unroll
    for (int mi = 0; mi < 4; mi++)
      af[mi] = *(const v8s*)&As[(wm + mi * 16 + ln) * 32 + quad * 8];
#pragma unroll
    for (int ni = 0; ni < 4; ni++)
      bfr[ni] = *(const v8s*)&Bs[(wn + ni * 16 + ln) * 32 + quad * 8];
#pragma unroll
    for (int mi = 0; mi < 4; mi++)
#pragma unroll
      for (int ni = 0; ni < 4; ni++)
        acc[mi][ni] = mfma16x16x32(af[mi], bfr[ni], acc[mi][ni]);
  }

#pragma unroll
  for (int ni = 0; ni < 4; ni++) {
    const int col = n0 + wn + ni * 16 + ln;
    if (EPI == 3) {
      const int proj = col >> 10, w = col & 1023;
      const float* bp = proj == 0 ? bias0 : (proj == 1 ? bias1 : bias2);
      const float bb = bp[w];
      const int hidx = w >> 6, hd = w & 63;
      if (proj == 2) {
        // v transposed: [b*16+h][hd][2048], ushort4-packed along s
#pragma unroll
        for (int mi = 0; mi < 4; mi++) {
          const int row0 = m0 + wm + mi * 16 + quad * 4;
          const int b_ = row0 >> 11, s = row0 & 2047;
          ushort4 pk;
          pk.x = b2u(finz(acc[mi][ni][0] + bb, 1e4f));
          pk.y = b2u(finz(acc[mi][ni][1] + bb, 1e4f));
          pk.z = b2u(finz(acc[mi][ni][2] + bb, 1e4f));
          pk.w = b2u(finz(acc[mi][ni][3] + bb, 1e4f));
          *(ushort4*)((ushort*)C2v +
                      (((long)(b_ * 16 + hidx)) * 64 + hd) * 2048 + s) = pk;
        }
      } else {
        bf16* op = proj == 0 ? (bf16*)C0v : C1;
        const float sc = proj == 0 ? 0.18033688f : 1.0f;  // 0.125*log2(e)
#pragma unroll
        for (int mi = 0; mi < 4; mi++)
#pragma unroll
          for (int r = 0; r < 4; r++) {
            const int row = m0 + wm + mi * 16 + quad * 4 + r;
            const int b_ = row >> 11, s = row & 2047;
            op[(((long)(b_ * 16 + hidx)) * 2048 + s) * 64 + hd] =
                f2b(finz((acc[mi][ni][r] + bb) * sc, 1e4f));
          }
      }
    } else {
      const float bb = bias0[col];
#pragma unroll
      for (int mi = 0; mi < 4; mi++)
#pragma unroll
        for (int r = 0; r < 4; r++) {
          const int row = m0 + wm + mi * 16 + quad * 4 + r;
          float vv = acc[mi][ni][r] + bb;
          if (EPI == 2) {
            vv = gelu_exact(vv);
            vv += b2f(((const bf16*)residv)[(long)row * N + col]);
            ((float*)C0v)[(long)row * N + col] = finz(vv, 1e5f);
          } else {
            if (EPI == 1) vv += ((const float*)residv)[(long)row * N + col];
            const float sent = EPI == 0 ? 4e4f : 2e4f;
            ((bf16*)C0v)[(long)row * N + col] = f2b(finz(vv, sent));
          }
        }
    }
  }
}

// ---------------------------------------------------------------------------
// Flash attention v4: LDS-staged K/V, 2x occupancy.
// grid 1024 blocks (16 q-blocks x 64 bh, XCD-clustered: 8 bh per XCD so each
// XCD's K/V working set = 4 MB = its L2). 4 waves x 32 q-rows = 128 rows/blk.
// Per kv-tile (64 keys): K-tile (8KB) + V^T-tile (8KB) staged ONCE per block
// into LDS via global_load_lds w=16 (double-buffered, stage t+1 issued before
// compute t -> latency hidden; one __syncthreads per tile). XOR swizzle
// byte^=(row&7)<<4 applied on the GLOBAL source (linear LDS dest, m173
// pattern) + same XOR on ds_read side -> no 16/32-way bank conflicts.
// S^T = K.Q^T register softmax as before; q pre-scaled by 0.125*log2e.
// q,k: [B,H,S,64]; vt: [B,H,64,S]. Out: [B,S,D] bf16.
// ---------------------------------------------------------------------------
__global__ __launch_bounds__(256, 4)
void attn_kernel(const bf16* __restrict__ q, const bf16* __restrict__ k,
                 const bf16* __restrict__ vt, bf16* __restrict__ o) {
  __shared__ bf16 Ks[2][64 * 64];
  __shared__ bf16 Vs[2][64 * 64];
  const int t = threadIdx.x, wave = t >> 6, lane = t & 63;
  const int quad = lane >> 4, ln = lane & 15;
  // XCD-clustered decode (dispatch round-robins id%8 across XCDs):
  const int id = blockIdx.x;
  const int bh = ((id & 7) << 3) | ((id >> 3) >> 4);  // 8 consecutive bh/XCD
  const int qb = (id >> 3) & 15;
  const int q0 = qb * 128 + wave * 32;
  const long base = (long)bh * (2048 * 64);

  // Q as B-operand frags (register-resident)
  v8s qf[2][2];
#pragma unroll
  for (int mi = 0; mi < 2; mi++)
#pragma unroll
    for (int kc = 0; kc < 2; kc++)
      qf[mi][kc] = *(const v8s*)(q + base + (long)(q0 + mi * 16 + ln) * 64 +
                                 kc * 32 + quad * 8);

  v4f accO[2][4];  // [mi][nh]: O^T tile, col=ln (q-row), row=quad*4+r (hd)
  float m2[2], l[2];
#pragma unroll
  for (int mi = 0; mi < 2; mi++) {
#pragma unroll
    for (int nh = 0; nh < 4; nh++) accO[mi][nh] = v4f{0.f, 0.f, 0.f, 0.f};
    m2[mi] = -1e30f;
    l[mi] = 0.f;
  }

  // staging offsets (loop-invariant). Linear LDS off; inverse-swizzled src.
  const int o0 = t * 16, o1 = t * 16 + 4096;
  const int ks0 = o0 ^ (((o0 >> 7) & 7) << 4);
  const int ks1 = o1 ^ (((o1 >> 7) & 7) << 4);
  const int h0 = o0 >> 7, h1 = o1 >> 7;
  const int vs0 = h0 * 4096 + ((o0 ^ ((h0 & 7) << 4)) & 127);
  const int vs1 = h1 * 4096 + ((o1 ^ ((h1 & 7) << 4)) & 127);
  const char* kgb = (const char*)(k + base);
  const char* vgb = (const char*)(vt + base);

  // prologue: stage tile 0 into buffer 0
  {
    char* kl = (char*)&Ks[0][0];
    char* vl = (char*)&Vs[0][0];
    load_lds16(kgb + ks0, kl + o0);
    load_lds16(kgb + ks1, kl + o1);
    load_lds16(vgb + vs0, vl + o0);
    load_lds16(vgb + vs1, vl + o1);
  }

  for (int it = 0; it < 32; ++it) {
    const int bf = it & 1;
    __syncthreads();  // staging(bf) drained; all waves done reading bf^1
    if (it + 1 < 32) {
      const char* kg = kgb + (long)(it + 1) * (64 * 128);  // 8KB per K-tile
      const char* vg = vgb + (long)(it + 1) * 128;         // 64 keys * 2B
      char* kl = (char*)&Ks[bf ^ 1][0];
      char* vl = (char*)&Vs[bf ^ 1][0];
      load_lds16(kg + ks0, kl + o0);
      load_lds16(kg + ks1, kl + o1);
      load_lds16(vg + vs0, vl + o0);
      load_lds16(vg + vs1, vl + o1);
    }
    const char* Kb = (const char*)&Ks[bf][0];
    const char* Vb = (const char*)&Vs[bf][0];

    // S^T tiles: st[mi][ni] at lane: key = ni*16+quad*4+r, qrow = mi*16+ln
    v4f st[2][4];
    __builtin_amdgcn_s_setprio(1);
#pragma unroll
    for (int ni = 0; ni < 4; ni++) {
      const int r = ni * 16 + ln;
      const int sw = (r & 7) << 4;
      v8s k0 = *(const v8s*)(Kb + ((r * 128 + quad * 16) ^ sw));
      v8s k1 = *(const v8s*)(Kb + ((r * 128 + 64 + quad * 16) ^ sw));
#pragma unroll
      for (int mi = 0; mi < 2; mi++) {
        v4f z = v4f{0.f, 0.f, 0.f, 0.f};
        z = mfma16x16x32(k0, qf[mi][0], z);
        st[mi][ni] = mfma16x16x32(k1, qf[mi][1], z);
      }
    }
    __builtin_amdgcn_s_setprio(0);

    // online softmax -> P^T packed straight into 16x16x16 B-frags
    v4s pf[2][4];
#pragma unroll
    for (int mi = 0; mi < 2; mi++) {
      float mx = st[mi][0][0];
#pragma unroll
      for (int ni = 0; ni < 4; ni++)
#pragma unroll
        for (int r = 0; r < 4; r++) mx = fmaxf(mx, st[mi][ni][r]);
      mx = fmaxf(mx, __shfl_xor(mx, 16));
      mx = fmaxf(mx, __shfl_xor(mx, 32));
      const float mo = m2[mi];
      const float mn = fmaxf(mo, mx);
      const float al = fexp2(mo - mn);
      m2[mi] = mn;
      l[mi] *= al;
#pragma unroll
      for (int nh = 0; nh < 4; nh++)
#pragma unroll
        for (int r = 0; r < 4; r++) accO[mi][nh][r] *= al;
      float rs = 0.f;
#pragma unroll
      for (int ni = 0; ni < 4; ni++) {
        v4s p4;
#pragma unroll
        for (int r = 0; r < 4; r++) {
          float p = fexp2(st[mi][ni][r] - mn);
          rs += p;
          p4[r] = (short)b2u(p);
        }
        pf[mi][ni] = p4;
      }
      rs += __shfl_xor(rs, 16);
      rs += __shfl_xor(rs, 32);
      l[mi] += rs;
    }

    // O^T += V^T . P^T  (A = V^T frag from LDS, B = P^T frag)
    __builtin_amdgcn_s_setprio(1);
#pragma unroll
    for (int nh = 0; nh < 4; nh++) {
      const int row = nh * 16 + ln;
      const int sw = (row & 7) << 4;
#pragma unroll
      for (int ni = 0; ni < 4; ni++) {
        v4s vv = *(const v4s*)(Vb + ((row * 128 + ni * 32 + quad * 8) ^ sw));
#pragma unroll
        for (int mi = 0; mi < 2; mi++)
          accO[mi][nh] = mfma16x16x16(vv, pf[mi][ni], accO[mi][nh]);
      }
    }
    __builtin_amdgcn_s_setprio(0);
  }

  // epilogue: o[b][s=q0+mi*16+ln][h*64 + nh*16+quad*4+r] = accO/l
  const int b_ = bh >> 4, h_ = bh & 15;
#pragma unroll
  for (int mi = 0; mi < 2; mi++) {
    const float inv = 1.0f / l[mi];
    const int s = q0 + mi * 16 + ln;
#pragma unroll
    for (int nh = 0; nh < 4; nh++) {
      ushort4 pk;
      pk.x = b2u(finz(accO[mi][nh][0] * inv, 5000.f));
      pk.y = b2u(finz(accO[mi][nh][1] * inv, 5000.f));
      pk.z = b2u(finz(accO[mi][nh][2] * inv, 5000.f));
      pk.w = b2u(finz(accO[mi][nh][3] * inv, 5000.f));
      *(ushort4*)((ushort*)o + ((long)(b_ * 2048 + s)) * 1024 + h_ * 64 +
                  nh * 16 + quad * 4) = pk;
    }
  }
}

// ---------------------------------------------------------------------------
extern "C" void kernel_launch(void* const* d_in, const int* in_sizes, int n_in,
                              void* d_out, int out_size, void* d_ws,
                              size_t ws_size, hipStream_t stream) {
  const float* x   = (const float*)d_in[0];
  const float* Wq  = (const float*)d_in[1];
  const float* bq  = (const float*)d_in[2];
  const float* Wk  = (const float*)d_in[3];
  const float* bk  = (const float*)d_in[4];
  const float* Wv  = (const float*)d_in[5];
  const float* bv  = (const float*)d_in[6];
  const float* Wo  = (const float*)d_in[7];
  const float* bo  = (const float*)d_in[8];
  const float* W1  = (const float*)d_in[9];
  const float* b1  = (const float*)d_in[10];
  const float* W2  = (const float*)d_in[11];
  const float* b2  = (const float*)d_in[12];
  const float* g1  = (const float*)d_in[13];
  const float* be1 = (const float*)d_in[14];
  const float* g2  = (const float*)d_in[15];
  const float* be2 = (const float*)d_in[16];
  float* out = (float*)d_out;

  const size_t MB = 1024 * 1024;
  if (ws_size < 104 * MB) return;
  char* W = (char*)d_ws;
  bf16* wqt = (bf16*)(W + 0 * MB);
  bf16* wkt = (bf16*)(W + 2 * MB);
  bf16* wvt = (bf16*)(W + 4 * MB);
  bf16* wot = (bf16*)(W + 6 * MB);
  bf16* h   = (bf16*)(W + 8 * MB);    // LN1 out; later LN2 out
  bf16* qb  = (bf16*)(W + 24 * MB);   // dead after attn
  bf16* kb  = (bf16*)(W + 40 * MB);   // dead after attn
  bf16* vb  = (bf16*)(W + 56 * MB);   // v TRANSPOSED [B,H,64,S]; dead after attn
  bf16* ao  = (bf16*)(W + 72 * MB);   // dead after Wo-gemm
  bf16* x1  = (bf16*)(W + 88 * MB);   // live to end
  bf16* w1t = (bf16*)(W + 24 * MB);   // after attn (qb slot)
  bf16* w2t = (bf16*)(W + 32 * MB);
  bf16* tbc = (bf16*)(W + 40 * MB);   // FFN mid chunk [4096][4096]

  repack_qkv<<<4096, 256, 0, stream>>>(Wq, wqt);
  repack_qkv<<<4096, 256, 0, stream>>>(Wk, wkt);
  repack_qkv<<<4096, 256, 0, stream>>>(Wv, wvt);
  transpose_f2b<<<dim3(32, 32), 256, 0, stream>>>(Wo, wot, 1024, 1024);

  // 1) h = LN1(x)
  ln_kernel<float><<<8192, 256, 0, stream>>>(x, g1, be1, h);
  // 2) q,k,v = h @ Wqkv + b  (q scaled; q,k -> [B,H,S,64]; v -> [B,H,64,S])
  gemm_bt<3><<<dim3(24, 64), 256, 0, stream>>>(h, wqt, bq, bk, bv, nullptr,
                                               qb, kb, vb, 8192, 3072, 1024);
  // 3) flash attention -> ao [B,S,D]
  attn_kernel<<<dim3(1024), 256, 0, stream>>>(qb, kb, vb, ao);
  // 4) x1 = x + ao @ Wo + bo
  gemm_bt<1><<<dim3(8, 64), 256, 0, stream>>>(ao, wot, bo, nullptr, nullptr, x,
                                              x1, nullptr, nullptr, 8192, 1024, 1024);
  transpose_f2b<<<dim3(128, 32), 256, 0, stream>>>(W1, w1t, 1024, 4096);
  transpose_f2b<<<dim3(32, 128), 256, 0, stream>>>(W2, w2t, 4096, 1024);
  // 5) h2 = LN2(x1)
  ln_kernel<bf16><<<8192, 256, 0, stream>>>(x1, g2, be2, h);
  // 6/7) FFN, M-chunked (2 x 4096 rows); final out FP32
  for (int c = 0; c < 2; c++) {
    const long moff = (long)c * 4096 * 1024;
    gemm_bt<0><<<dim3(32, 32), 256, 0, stream>>>(h + moff, w1t, b1, nullptr,
                                                 nullptr, nullptr, tbc, nullptr,
                                                 nullptr, 4096, 4096, 1024);
    gemm_bt<2><<<dim3(8, 32), 256, 0, stream>>>(tbc, w2t, b2, nullptr, nullptr,
                                                x1 + moff, out + moff, nullptr,
                                                nullptr, 4096, 1024, 4096);
  }
}

// Round 4
// 653.748 us; speedup vs baseline: 1.2036x; 1.1382x over previous
//
#include <hip/hip_runtime.h>
#include <hip/hip_bf16.h>
#include <cmath>

typedef __hip_bfloat16 bf16;
typedef float v4f __attribute__((ext_vector_type(4)));
typedef short v8s __attribute__((ext_vector_type(8)));   // 8 x bf16 bits
typedef short v4s __attribute__((ext_vector_type(4)));   // 4 x bf16 bits

__device__ __forceinline__ void load_lds16(const void* g, void* l) {
  __builtin_amdgcn_global_load_lds(
      (const __attribute__((address_space(1))) char*)g,
      (__attribute__((address_space(3))) char*)l, 16, 0, 0);
}
__device__ __forceinline__ v4f mfma16x16x32(v8s a, v8s b, v4f c) {
  return __builtin_amdgcn_mfma_f32_16x16x32_bf16(a, b, c, 0, 0, 0);
}
__device__ __forceinline__ v4f mfma16x16x16(v4s a, v4s b, v4f c) {
#if __has_builtin(__builtin_amdgcn_mfma_f32_16x16x16_bf16)
  return __builtin_amdgcn_mfma_f32_16x16x16_bf16(a, b, c, 0, 0, 0);
#elif __has_builtin(__builtin_amdgcn_mfma_f32_16x16x16bf16_1k)
  return __builtin_amdgcn_mfma_f32_16x16x16bf16_1k(a, b, c, 0, 0, 0);
#else
  v4f d;
  asm("v_mfma_f32_16x16x16_bf16 %0, %1, %2, %3"
      : "=v"(d) : "v"(a), "v"(b), "v"(c));
  return d;
#endif
}
__device__ __forceinline__ float b2f(bf16 x) { return __bfloat162float(x); }
__device__ __forceinline__ bf16 f2b(float x) { return __float2bfloat16(x); }
__device__ __forceinline__ ushort b2u(float x) {
  bf16 h = f2b(x);
  return *(ushort*)&h;
}
__device__ __forceinline__ float fexp2(float x) {
#if __has_builtin(__builtin_amdgcn_exp2f)
  return __builtin_amdgcn_exp2f(x);
#else
  return exp2f(x);
#endif
}
__device__ __forceinline__ float gelu_exact(float x) {
  return 0.5f * x * (1.0f + erff(x * 0.70710678118654752f));
}
__device__ __forceinline__ float finz(float v, float sent) {
  return __builtin_isfinite(v) ? v : sent;
}
__device__ __forceinline__ float u2f(ushort u) {
  return __uint_as_float(((unsigned)u) << 16);
}
__device__ __forceinline__ float4 load4f(const float* p) {
  return *(const float4*)p;
}
__device__ __forceinline__ float4 load4f(const bf16* p) {
  ushort4 u = *(const ushort4*)p;
  return make_float4(u2f(u.x), u2f(u.y), u2f(u.z), u2f(u.w));
}

// ---------------------------------------------------------------------------
// LayerNorm: one block per row of 1024, fp32 stats, bf16 out.
// ---------------------------------------------------------------------------
template <typename TI>
__global__ __launch_bounds__(256)
void ln_kernel(const TI* __restrict__ x, const float* __restrict__ g,
               const float* __restrict__ b, bf16* __restrict__ out) {
  __shared__ float red[8];
  __shared__ float stat[2];
  const int row = blockIdx.x, t = threadIdx.x;
  const int wave = t >> 6, lane = t & 63;
  float4 v = load4f(x + (long)row * 1024 + t * 4);
  float s = v.x + v.y + v.z + v.w;
  float s2 = v.x * v.x + v.y * v.y + v.z * v.z + v.w * v.w;
#pragma unroll
  for (int off = 32; off > 0; off >>= 1) {
    s += __shfl_down(s, off);
    s2 += __shfl_down(s2, off);
  }
  if (lane == 0) { red[wave * 2] = s; red[wave * 2 + 1] = s2; }
  __syncthreads();
  if (t == 0) {
    float S = red[0] + red[2] + red[4] + red[6];
    float S2 = red[1] + red[3] + red[5] + red[7];
    float mean = S * (1.0f / 1024.0f);
    float var = S2 * (1.0f / 1024.0f) - mean * mean;
    stat[0] = mean;
    stat[1] = rsqrtf(var + 1e-5f);
  }
  __syncthreads();
  const float mean = stat[0], rs = stat[1];
  bf16* orow = out + (long)row * 1024;
  const int c = t * 4;
  float4 gg = *(const float4*)(g + c);
  float4 bb = *(const float4*)(b + c);
  orow[c + 0] = f2b(finz((v.x - mean) * rs * gg.x + bb.x, 3000.f));
  orow[c + 1] = f2b(finz((v.y - mean) * rs * gg.y + bb.y, 3000.f));
  orow[c + 2] = f2b(finz((v.z - mean) * rs * gg.z + bb.z, 3000.f));
  orow[c + 3] = f2b(finz((v.w - mean) * rs * gg.w + bb.w, 3000.f));
}

// ---------------------------------------------------------------------------
// Repack Wq/Wk/Wv fp32 [H=16, D=1024, HD=64] -> bf16 Wt[n=h*64+kk][d]
// ---------------------------------------------------------------------------
__global__ __launch_bounds__(256)
void repack_qkv(const float* __restrict__ w, bf16* __restrict__ wt) {
  long i = (long)blockIdx.x * 256 + threadIdx.x;
  int n = (int)(i >> 10), d = (int)(i & 1023);
  int h = n >> 6, kk = n & 63;
  wt[i] = f2b(w[((long)h * 1024 + d) * 64 + kk]);
}

// ---------------------------------------------------------------------------
// Tiled transpose fp32 -> bf16: out[c*R + r] = in[r*C + c]
// ---------------------------------------------------------------------------
__global__ __launch_bounds__(256)
void transpose_f2b(const float* __restrict__ in, bf16* __restrict__ out,
                   int R, int C) {
  __shared__ float tile[32][33];
  const int tx = threadIdx.x & 31, ty = threadIdx.x >> 5;
  const int r0 = blockIdx.y * 32, c0 = blockIdx.x * 32;
#pragma unroll
  for (int i = ty; i < 32; i += 8) tile[i][tx] = in[(long)(r0 + i) * C + c0 + tx];
  __syncthreads();
#pragma unroll
  for (int i = ty; i < 32; i += 8)
    out[(long)(c0 + i) * R + r0 + tx] = f2b(tile[tx][i]);
}

// ---------------------------------------------------------------------------
// GEMM C[M,N] = A[M,K] @ Bt[N,K]^T (128x128, BK=32, async global_load_lds).
// EPI: 0=+bias (bf16)  1=+bias+fp32 resid (bf16)  2=gelu+bf16 resid (FP32)
//      3=QKV scatter: q (PRE-SCALED by 0.125*log2e), k -> [B,H,S,64];
//        v -> TRANSPOSED [B,H,64,S]
// ---------------------------------------------------------------------------
template <int EPI>
__global__ __launch_bounds__(256)
void gemm_bt(const bf16* __restrict__ A, const bf16* __restrict__ Bt,
             const float* __restrict__ bias0, const float* __restrict__ bias1,
             const float* __restrict__ bias2, const void* __restrict__ residv,
             void* __restrict__ C0v, bf16* __restrict__ C1, bf16* __restrict__ C2v,
             int M, int N, int K) {
  __shared__ bf16 As[128 * 32];
  __shared__ bf16 Bs[128 * 32];
  const int t = threadIdx.x;
  const int wave = t >> 6, lane = t & 63, quad = lane >> 4, ln = lane & 15;
  const int m0 = blockIdx.y * 128, n0 = blockIdx.x * 128;
  const int wm = (wave >> 1) * 64, wn = (wave & 1) * 64;

  v4f acc[4][4];
#pragma unroll
  for (int i = 0; i < 4; i++)
#pragma unroll
    for (int j = 0; j < 4; j++) acc[i][j] = v4f{0.f, 0.f, 0.f, 0.f};

  const int e0 = t * 8, e1 = t * 8 + 2048;
  const int ra0 = e0 >> 5, ca0 = e0 & 31, ra1 = e1 >> 5, ca1 = e1 & 31;
  const bf16* Ab = A + (long)m0 * K;
  const bf16* Bb = Bt + (long)n0 * K;

  for (int k0 = 0; k0 < K; k0 += 32) {
    __syncthreads();
    load_lds16(Ab + (long)ra0 * K + k0 + ca0, &As[e0]);
    load_lds16(Ab + (long)ra1 * K + k0 + ca1, &As[e1]);
    load_lds16(Bb + (long)ra0 * K + k0 + ca0, &Bs[e0]);
    load_lds16(Bb + (long)ra1 * K + k0 + ca1, &Bs[e1]);
    __syncthreads();
    v8s af[4], bfr[4];
#pragma unroll
    for (int mi = 0; mi < 4; mi++)
      af[mi] = *(const v8s*)&As[(wm + mi * 16 + ln) * 32 + quad * 8];
#pragma unroll
    for (int ni = 0; ni < 4; ni++)
      bfr[ni] = *(const v8s*)&Bs[(wn + ni * 16 + ln) * 32 + quad * 8];
#pragma unroll
    for (int mi = 0; mi < 4; mi++)
#pragma unroll
      for (int ni = 0; ni < 4; ni++)
        acc[mi][ni] = mfma16x16x32(af[mi], bfr[ni], acc[mi][ni]);
  }

#pragma unroll
  for (int ni = 0; ni < 4; ni++) {
    const int col = n0 + wn + ni * 16 + ln;
    if (EPI == 3) {
      const int proj = col >> 10, w = col & 1023;
      const float* bp = proj == 0 ? bias0 : (proj == 1 ? bias1 : bias2);
      const float bb = bp[w];
      const int hidx = w >> 6, hd = w & 63;
      if (proj == 2) {
        // v transposed: [b*16+h][hd][2048], ushort4-packed along s
#pragma unroll
        for (int mi = 0; mi < 4; mi++) {
          const int row0 = m0 + wm + mi * 16 + quad * 4;
          const int b_ = row0 >> 11, s = row0 & 2047;
          ushort4 pk;
          pk.x = b2u(finz(acc[mi][ni][0] + bb, 1e4f));
          pk.y = b2u(finz(acc[mi][ni][1] + bb, 1e4f));
          pk.z = b2u(finz(acc[mi][ni][2] + bb, 1e4f));
          pk.w = b2u(finz(acc[mi][ni][3] + bb, 1e4f));
          *(ushort4*)((ushort*)C2v +
                      (((long)(b_ * 16 + hidx)) * 64 + hd) * 2048 + s) = pk;
        }
      } else {
        bf16* op = proj == 0 ? (bf16*)C0v : C1;
        const float sc = proj == 0 ? 0.18033688f : 1.0f;  // 0.125*log2(e)
#pragma unroll
        for (int mi = 0; mi < 4; mi++)
#pragma unroll
          for (int r = 0; r < 4; r++) {
            const int row = m0 + wm + mi * 16 + quad * 4 + r;
            const int b_ = row >> 11, s = row & 2047;
            op[(((long)(b_ * 16 + hidx)) * 2048 + s) * 64 + hd] =
                f2b(finz((acc[mi][ni][r] + bb) * sc, 1e4f));
          }
      }
    } else {
      const float bb = bias0[col];
#pragma unroll
      for (int mi = 0; mi < 4; mi++)
#pragma unroll
        for (int r = 0; r < 4; r++) {
          const int row = m0 + wm + mi * 16 + quad * 4 + r;
          float vv = acc[mi][ni][r] + bb;
          if (EPI == 2) {
            vv = gelu_exact(vv);
            vv += b2f(((const bf16*)residv)[(long)row * N + col]);
            ((float*)C0v)[(long)row * N + col] = finz(vv, 1e5f);
          } else {
            if (EPI == 1) vv += ((const float*)residv)[(long)row * N + col];
            const float sent = EPI == 0 ? 4e4f : 2e4f;
            ((bf16*)C0v)[(long)row * N + col] = f2b(finz(vv, sent));
          }
        }
    }
  }
}

// ---------------------------------------------------------------------------
// GEMM 64x64-tile variant for skinny outputs (N=1024): 4 waves, 2x2 subtiles,
// low VGPR -> 8 blocks/CU (vs 1-2 blocks/CU with the 128x128 tile).
// EPI: 1=+bias+fp32 resid (bf16 out)  2=gelu+bf16 resid (FP32 out)
// ---------------------------------------------------------------------------
template <int EPI>
__global__ __launch_bounds__(256, 8)
void gemm_bt64(const bf16* __restrict__ A, const bf16* __restrict__ Bt,
               const float* __restrict__ bias0, const void* __restrict__ residv,
               void* __restrict__ C0v, int M, int N, int K) {
  __shared__ bf16 As[64 * 32];
  __shared__ bf16 Bs[64 * 32];
  const int t = threadIdx.x;
  const int wave = t >> 6, lane = t & 63, quad = lane >> 4, ln = lane & 15;
  const int m0 = blockIdx.y * 64, n0 = blockIdx.x * 64;
  const int wm = (wave >> 1) * 32, wn = (wave & 1) * 32;

  v4f acc[2][2];
#pragma unroll
  for (int i = 0; i < 2; i++)
#pragma unroll
    for (int j = 0; j < 2; j++) acc[i][j] = v4f{0.f, 0.f, 0.f, 0.f};

  const int ra = t >> 2, ca = (t & 3) * 8;      // 64 rows x 32 cols, 16B/lane
  const bf16* Ab = A + (long)(m0 + ra) * K + ca;
  const bf16* Bb = Bt + (long)(n0 + ra) * K + ca;
  bf16* Asd = &As[ra * 32 + ca];                // == byte offset t*16 (linear)
  bf16* Bsd = &Bs[ra * 32 + ca];

  for (int k0 = 0; k0 < K; k0 += 32) {
    __syncthreads();
    load_lds16(Ab + k0, Asd);
    load_lds16(Bb + k0, Bsd);
    __syncthreads();
    v8s af[2], bfr[2];
#pragma unroll
    for (int mi = 0; mi < 2; mi++)
      af[mi] = *(const v8s*)&As[(wm + mi * 16 + ln) * 32 + quad * 8];
#pragma unroll
    for (int ni = 0; ni < 2; ni++)
      bfr[ni] = *(const v8s*)&Bs[(wn + ni * 16 + ln) * 32 + quad * 8];
#pragma unroll
    for (int mi = 0; mi < 2; mi++)
#pragma unroll
      for (int ni = 0; ni < 2; ni++)
        acc[mi][ni] = mfma16x16x32(af[mi], bfr[ni], acc[mi][ni]);
  }

#pragma unroll
  for (int ni = 0; ni < 2; ni++) {
    const int col = n0 + wn + ni * 16 + ln;
    const float bb = bias0[col];
#pragma unroll
    for (int mi = 0; mi < 2; mi++)
#pragma unroll
      for (int r = 0; r < 4; r++) {
        const int row = m0 + wm + mi * 16 + quad * 4 + r;
        float vv = acc[mi][ni][r] + bb;
        if (EPI == 2) {
          vv = gelu_exact(vv);
          vv += b2f(((const bf16*)residv)[(long)row * N + col]);
          ((float*)C0v)[(long)row * N + col] = finz(vv, 1e5f);
        } else {
          vv += ((const float*)residv)[(long)row * N + col];
          ((bf16*)C0v)[(long)row * N + col] = f2b(finz(vv, 2e4f));
        }
      }
  }
}

// ---------------------------------------------------------------------------
// Flash attention v5: LDS-staged K/V + defer-max (T13) + deferred-l.
// grid 1024 blocks (16 q-blocks x 64 bh, XCD-clustered). 4 waves x 32 q-rows.
// Softmax denominator kept as PER-LANE partial (cross-quad reduce ONCE in
// epilogue, not per tile). Rescale of accO skipped when the tile max stays
// within THR=8 of the running max (P bounded by 2^8; f32 accum absorbs it).
// q,k: [B,H,S,64]; vt: [B,H,64,S]. Out: [B,S,D] bf16.
// ---------------------------------------------------------------------------
__global__ __launch_bounds__(256, 4)
void attn_kernel(const bf16* __restrict__ q, const bf16* __restrict__ k,
                 const bf16* __restrict__ vt, bf16* __restrict__ o) {
  __shared__ bf16 Ks[2][64 * 64];
  __shared__ bf16 Vs[2][64 * 64];
  const int t = threadIdx.x, wave = t >> 6, lane = t & 63;
  const int quad = lane >> 4, ln = lane & 15;
  const int id = blockIdx.x;
  const int bh = ((id & 7) << 3) | ((id >> 3) >> 4);  // 8 consecutive bh/XCD
  const int qb = (id >> 3) & 15;
  const int q0 = qb * 128 + wave * 32;
  const long base = (long)bh * (2048 * 64);

  // Q as B-operand frags (register-resident)
  v8s qf[2][2];
#pragma unroll
  for (int mi = 0; mi < 2; mi++)
#pragma unroll
    for (int kc = 0; kc < 2; kc++)
      qf[mi][kc] = *(const v8s*)(q + base + (long)(q0 + mi * 16 + ln) * 64 +
                                 kc * 32 + quad * 8);

  v4f accO[2][4];  // [mi][nh]: O^T tile, col=ln (q-row), row=quad*4+r (hd)
  float m2[2], lp[2];  // lp: PER-LANE partial denominator (this lane's keys)
#pragma unroll
  for (int mi = 0; mi < 2; mi++) {
#pragma unroll
    for (int nh = 0; nh < 4; nh++) accO[mi][nh] = v4f{0.f, 0.f, 0.f, 0.f};
    m2[mi] = -1e30f;
    lp[mi] = 0.f;
  }

  // staging offsets (loop-invariant). Linear LDS off; inverse-swizzled src.
  const int o0 = t * 16, o1 = t * 16 + 4096;
  const int ks0 = o0 ^ (((o0 >> 7) & 7) << 4);
  const int ks1 = o1 ^ (((o1 >> 7) & 7) << 4);
  const int h0 = o0 >> 7, h1 = o1 >> 7;
  const int vs0 = h0 * 4096 + ((o0 ^ ((h0 & 7) << 4)) & 127);
  const int vs1 = h1 * 4096 + ((o1 ^ ((h1 & 7) << 4)) & 127);
  const char* kgb = (const char*)(k + base);
  const char* vgb = (const char*)(vt + base);

  // prologue: stage tile 0 into buffer 0
  {
    char* kl = (char*)&Ks[0][0];
    char* vl = (char*)&Vs[0][0];
    load_lds16(kgb + ks0, kl + o0);
    load_lds16(kgb + ks1, kl + o1);
    load_lds16(vgb + vs0, vl + o0);
    load_lds16(vgb + vs1, vl + o1);
  }

  for (int it = 0; it < 32; ++it) {
    const int bf = it & 1;
    __syncthreads();  // staging(bf) drained; all waves done reading bf^1
    if (it + 1 < 32) {
      const char* kg = kgb + (long)(it + 1) * (64 * 128);  // 8KB per K-tile
      const char* vg = vgb + (long)(it + 1) * 128;         // 64 keys * 2B
      char* kl = (char*)&Ks[bf ^ 1][0];
      char* vl = (char*)&Vs[bf ^ 1][0];
      load_lds16(kg + ks0, kl + o0);
      load_lds16(kg + ks1, kl + o1);
      load_lds16(vg + vs0, vl + o0);
      load_lds16(vg + vs1, vl + o1);
    }
    const char* Kb = (const char*)&Ks[bf][0];
    const char* Vb = (const char*)&Vs[bf][0];

    // S^T tiles: st[mi][ni] at lane: key = ni*16+quad*4+r, qrow = mi*16+ln
    v4f st[2][4];
    __builtin_amdgcn_s_setprio(1);
#pragma unroll
    for (int ni = 0; ni < 4; ni++) {
      const int r = ni * 16 + ln;
      const int sw = (r & 7) << 4;
      v8s k0 = *(const v8s*)(Kb + ((r * 128 + quad * 16) ^ sw));
      v8s k1 = *(const v8s*)(Kb + ((r * 128 + 64 + quad * 16) ^ sw));
#pragma unroll
      for (int mi = 0; mi < 2; mi++) {
        v4f z = v4f{0.f, 0.f, 0.f, 0.f};
        z = mfma16x16x32(k0, qf[mi][0], z);
        st[mi][ni] = mfma16x16x32(k1, qf[mi][1], z);
      }
    }
    __builtin_amdgcn_s_setprio(0);

    // online softmax (defer-max, per-lane l) -> P^T packed into x16 B-frags
    v4s pf[2][4];
#pragma unroll
    for (int mi = 0; mi < 2; mi++) {
      // max as a tree (max3-fusable)
      float a0 = fmaxf(fmaxf(st[mi][0][0], st[mi][0][1]),
                       fmaxf(st[mi][0][2], st[mi][0][3]));
      float a1 = fmaxf(fmaxf(st[mi][1][0], st[mi][1][1]),
                       fmaxf(st[mi][1][2], st[mi][1][3]));
      float a2 = fmaxf(fmaxf(st[mi][2][0], st[mi][2][1]),
                       fmaxf(st[mi][2][2], st[mi][2][3]));
      float a3 = fmaxf(fmaxf(st[mi][3][0], st[mi][3][1]),
                       fmaxf(st[mi][3][2], st[mi][3][3]));
      float mx = fmaxf(fmaxf(a0, a1), fmaxf(a2, a3));
      mx = fmaxf(mx, __shfl_xor(mx, 16));
      mx = fmaxf(mx, __shfl_xor(mx, 32));
      const float mo = m2[mi];
      if (!__all(mx <= mo + 8.0f)) {  // T13: rescale only when max grew >THR
        const float mn = fmaxf(mo, mx);
        const float al = fexp2(mo - mn);
        m2[mi] = mn;
        lp[mi] *= al;
#pragma unroll
        for (int nh = 0; nh < 4; nh++)
#pragma unroll
          for (int r = 0; r < 4; r++) accO[mi][nh][r] *= al;
      }
      const float mu = m2[mi];
      float rs = 0.f;
#pragma unroll
      for (int ni = 0; ni < 4; ni++) {
        v4s p4;
#pragma unroll
        for (int r = 0; r < 4; r++) {
          float p = fexp2(st[mi][ni][r] - mu);
          rs += p;
          p4[r] = (short)b2u(p);
        }
        pf[mi][ni] = p4;
      }
      lp[mi] += rs;  // per-lane partial; cross-quad reduce deferred to epilogue
    }

    // O^T += V^T . P^T  (A = V^T frag from LDS, B = P^T frag)
    __builtin_amdgcn_s_setprio(1);
#pragma unroll
    for (int nh = 0; nh < 4; nh++) {
      const int row = nh * 16 + ln;
      const int sw = (row & 7) << 4;
#pragma unroll
      for (int ni = 0; ni < 4; ni++) {
        v4s vv = *(const v4s*)(Vb + ((row * 128 + ni * 32 + quad * 8) ^ sw));
#pragma unroll
        for (int mi = 0; mi < 2; mi++)
          accO[mi][nh] = mfma16x16x16(vv, pf[mi][ni], accO[mi][nh]);
      }
    }
    __builtin_amdgcn_s_setprio(0);
  }

  // epilogue: reduce per-lane l across quads, then write O
  const int b_ = bh >> 4, h_ = bh & 15;
#pragma unroll
  for (int mi = 0; mi < 2; mi++) {
    float lr = lp[mi];
    lr += __shfl_xor(lr, 16);
    lr += __shfl_xor(lr, 32);
    const float inv = 1.0f / lr;
    const int s = q0 + mi * 16 + ln;
#pragma unroll
    for (int nh = 0; nh < 4; nh++) {
      ushort4 pk;
      pk.x = b2u(finz(accO[mi][nh][0] * inv, 5000.f));
      pk.y = b2u(finz(accO[mi][nh][1] * inv, 5000.f));
      pk.z = b2u(finz(accO[mi][nh][2] * inv, 5000.f));
      pk.w = b2u(finz(accO[mi][nh][3] * inv, 5000.f));
      *(ushort4*)((ushort*)o + ((long)(b_ * 2048 + s)) * 1024 + h_ * 64 +
                  nh * 16 + quad * 4) = pk;
    }
  }
}

// ---------------------------------------------------------------------------
extern "C" void kernel_launch(void* const* d_in, const int* in_sizes, int n_in,
                              void* d_out, int out_size, void* d_ws,
                              size_t ws_size, hipStream_t stream) {
  const float* x   = (const float*)d_in[0];
  const float* Wq  = (const float*)d_in[1];
  const float* bq  = (const float*)d_in[2];
  const float* Wk  = (const float*)d_in[3];
  const float* bk  = (const float*)d_in[4];
  const float* Wv  = (const float*)d_in[5];
  const float* bv  = (const float*)d_in[6];
  const float* Wo  = (const float*)d_in[7];
  const float* bo  = (const float*)d_in[8];
  const float* W1  = (const float*)d_in[9];
  const float* b1  = (const float*)d_in[10];
  const float* W2  = (const float*)d_in[11];
  const float* b2  = (const float*)d_in[12];
  const float* g1  = (const float*)d_in[13];
  const float* be1 = (const float*)d_in[14];
  const float* g2  = (const float*)d_in[15];
  const float* be2 = (const float*)d_in[16];
  float* out = (float*)d_out;

  const size_t MB = 1024 * 1024;
  if (ws_size < 104 * MB) return;
  char* W = (char*)d_ws;
  bf16* wqt = (bf16*)(W + 0 * MB);
  bf16* wkt = (bf16*)(W + 2 * MB);
  bf16* wvt = (bf16*)(W + 4 * MB);
  bf16* wot = (bf16*)(W + 6 * MB);
  bf16* h   = (bf16*)(W + 8 * MB);    // LN1 out; later LN2 out (16MB)
  bf16* qb  = (bf16*)(W + 24 * MB);   // dead after attn
  bf16* kb  = (bf16*)(W + 40 * MB);   // dead after attn
  bf16* vb  = (bf16*)(W + 56 * MB);   // v TRANSPOSED [B,H,64,S]; dead after attn
  bf16* ao  = (bf16*)(W + 72 * MB);   // dead after Wo-gemm
  bf16* x1  = (bf16*)(W + 88 * MB);   // live to end (16MB, ends 104)
  bf16* w1t = (bf16*)(W + 24 * MB);   // after attn (qb slot), 24-32
  bf16* w2t = (bf16*)(W + 32 * MB);   // 32-40
  bf16* tbc = (bf16*)(W + 40 * MB);   // FFN mid chunk [4096][4096] = 32MB, 40-72

  repack_qkv<<<4096, 256, 0, stream>>>(Wq, wqt);
  repack_qkv<<<4096, 256, 0, stream>>>(Wk, wkt);
  repack_qkv<<<4096, 256, 0, stream>>>(Wv, wvt);
  transpose_f2b<<<dim3(32, 32), 256, 0, stream>>>(Wo, wot, 1024, 1024);

  // 1) h = LN1(x)
  ln_kernel<float><<<8192, 256, 0, stream>>>(x, g1, be1, h);
  // 2) q,k,v = h @ Wqkv + b  (q scaled; q,k -> [B,H,S,64]; v -> [B,H,64,S])
  gemm_bt<3><<<dim3(24, 64), 256, 0, stream>>>(h, wqt, bq, bk, bv, nullptr,
                                               qb, kb, vb, 8192, 3072, 1024);
  // 3) flash attention -> ao [B,S,D]
  attn_kernel<<<dim3(1024), 256, 0, stream>>>(qb, kb, vb, ao);
  // 4) x1 = x + ao @ Wo + bo  (64x64 tiles -> 2048 blocks, 8/CU)
  gemm_bt64<1><<<dim3(16, 128), 256, 0, stream>>>(ao, wot, bo, x, x1,
                                                  8192, 1024, 1024);
  transpose_f2b<<<dim3(128, 32), 256, 0, stream>>>(W1, w1t, 1024, 4096);
  transpose_f2b<<<dim3(32, 128), 256, 0, stream>>>(W2, w2t, 4096, 1024);
  // 5) h2 = LN2(x1)
  ln_kernel<bf16><<<8192, 256, 0, stream>>>(x1, g2, be2, h);
  // 6/7) FFN, M-chunked (2 x 4096 rows; tbc 32MB at 40-72, clear of x1@88-104)
  for (int c = 0; c < 2; c++) {
    const long moff = (long)c * 4096 * 1024;
    gemm_bt<0><<<dim3(32, 32), 256, 0, stream>>>(h + moff, w1t, b1, nullptr,
                                                 nullptr, nullptr, tbc, nullptr,
                                                 nullptr, 4096, 4096, 1024);
    gemm_bt64<2><<<dim3(16, 64), 256, 0, stream>>>(tbc, w2t, b2, x1 + moff,
                                                   out + moff, 4096, 1024, 4096);
  }
}

// Round 5
// 649.218 us; speedup vs baseline: 1.2120x; 1.0070x over previous
//
#include <hip/hip_runtime.h>
#include <hip/hip_bf16.h>
#include <cmath>

typedef __hip_bfloat16 bf16;
typedef float v4f __attribute__((ext_vector_type(4)));
typedef short v8s __attribute__((ext_vector_type(8)));   // 8 x bf16 bits
typedef short v4s __attribute__((ext_vector_type(4)));   // 4 x bf16 bits

__device__ __forceinline__ void load_lds16(const void* g, void* l) {
  __builtin_amdgcn_global_load_lds(
      (const __attribute__((address_space(1))) char*)g,
      (__attribute__((address_space(3))) char*)l, 16, 0, 0);
}
__device__ __forceinline__ v4f mfma16x16x32(v8s a, v8s b, v4f c) {
  return __builtin_amdgcn_mfma_f32_16x16x32_bf16(a, b, c, 0, 0, 0);
}
__device__ __forceinline__ v4f mfma16x16x16(v4s a, v4s b, v4f c) {
#if __has_builtin(__builtin_amdgcn_mfma_f32_16x16x16_bf16)
  return __builtin_amdgcn_mfma_f32_16x16x16_bf16(a, b, c, 0, 0, 0);
#elif __has_builtin(__builtin_amdgcn_mfma_f32_16x16x16bf16_1k)
  return __builtin_amdgcn_mfma_f32_16x16x16bf16_1k(a, b, c, 0, 0, 0);
#else
  v4f d;
  asm("v_mfma_f32_16x16x16_bf16 %0, %1, %2, %3"
      : "=v"(d) : "v"(a), "v"(b), "v"(c));
  return d;
#endif
}
__device__ __forceinline__ float b2f(bf16 x) { return __bfloat162float(x); }
__device__ __forceinline__ bf16 f2b(float x) { return __float2bfloat16(x); }
__device__ __forceinline__ ushort b2u(float x) {
  bf16 h = f2b(x);
  return *(ushort*)&h;
}
__device__ __forceinline__ float fexp2(float x) {
#if __has_builtin(__builtin_amdgcn_exp2f)
  return __builtin_amdgcn_exp2f(x);
#else
  return exp2f(x);
#endif
}
__device__ __forceinline__ float gelu_exact(float x) {
  return 0.5f * x * (1.0f + erff(x * 0.70710678118654752f));
}
__device__ __forceinline__ float finz(float v, float sent) {
  return __builtin_isfinite(v) ? v : sent;
}
__device__ __forceinline__ float u2f(ushort u) {
  return __uint_as_float(((unsigned)u) << 16);
}
__device__ __forceinline__ float4 load4f(const float* p) {
  return *(const float4*)p;
}
__device__ __forceinline__ float4 load4f(const bf16* p) {
  ushort4 u = *(const ushort4*)p;
  return make_float4(u2f(u.x), u2f(u.y), u2f(u.z), u2f(u.w));
}

// ---------------------------------------------------------------------------
// LayerNorm: one block per row of 1024, fp32 stats, bf16 out.
// ---------------------------------------------------------------------------
template <typename TI>
__global__ __launch_bounds__(256)
void ln_kernel(const TI* __restrict__ x, const float* __restrict__ g,
               const float* __restrict__ b, bf16* __restrict__ out) {
  __shared__ float red[8];
  __shared__ float stat[2];
  const int row = blockIdx.x, t = threadIdx.x;
  const int wave = t >> 6, lane = t & 63;
  float4 v = load4f(x + (long)row * 1024 + t * 4);
  float s = v.x + v.y + v.z + v.w;
  float s2 = v.x * v.x + v.y * v.y + v.z * v.z + v.w * v.w;
#pragma unroll
  for (int off = 32; off > 0; off >>= 1) {
    s += __shfl_down(s, off);
    s2 += __shfl_down(s2, off);
  }
  if (lane == 0) { red[wave * 2] = s; red[wave * 2 + 1] = s2; }
  __syncthreads();
  if (t == 0) {
    float S = red[0] + red[2] + red[4] + red[6];
    float S2 = red[1] + red[3] + red[5] + red[7];
    float mean = S * (1.0f / 1024.0f);
    float var = S2 * (1.0f / 1024.0f) - mean * mean;
    stat[0] = mean;
    stat[1] = rsqrtf(var + 1e-5f);
  }
  __syncthreads();
  const float mean = stat[0], rs = stat[1];
  bf16* orow = out + (long)row * 1024;
  const int c = t * 4;
  float4 gg = *(const float4*)(g + c);
  float4 bb = *(const float4*)(b + c);
  orow[c + 0] = f2b(finz((v.x - mean) * rs * gg.x + bb.x, 3000.f));
  orow[c + 1] = f2b(finz((v.y - mean) * rs * gg.y + bb.y, 3000.f));
  orow[c + 2] = f2b(finz((v.z - mean) * rs * gg.z + bb.z, 3000.f));
  orow[c + 3] = f2b(finz((v.w - mean) * rs * gg.w + bb.w, 3000.f));
}

// ---------------------------------------------------------------------------
// Repack Wq/Wk/Wv fp32 [H=16, D=1024, HD=64] -> bf16 Wt[n=h*64+kk][d]
// ---------------------------------------------------------------------------
__global__ __launch_bounds__(256)
void repack_qkv(const float* __restrict__ w, bf16* __restrict__ wt) {
  long i = (long)blockIdx.x * 256 + threadIdx.x;
  int n = (int)(i >> 10), d = (int)(i & 1023);
  int h = n >> 6, kk = n & 63;
  wt[i] = f2b(w[((long)h * 1024 + d) * 64 + kk]);
}

// ---------------------------------------------------------------------------
// Tiled transpose fp32 -> bf16: out[c*R + r] = in[r*C + c]
// ---------------------------------------------------------------------------
__global__ __launch_bounds__(256)
void transpose_f2b(const float* __restrict__ in, bf16* __restrict__ out,
                   int R, int C) {
  __shared__ float tile[32][33];
  const int tx = threadIdx.x & 31, ty = threadIdx.x >> 5;
  const int r0 = blockIdx.y * 32, c0 = blockIdx.x * 32;
#pragma unroll
  for (int i = ty; i < 32; i += 8) tile[i][tx] = in[(long)(r0 + i) * C + c0 + tx];
  __syncthreads();
#pragma unroll
  for (int i = ty; i < 32; i += 8)
    out[(long)(c0 + i) * R + r0 + tx] = f2b(tile[tx][i]);
}

// ---------------------------------------------------------------------------
// GEMM C[M,N] = A[M,K] @ Bt[N,K]^T (128x128, BK=32, DOUBLE-BUFFERED LDS:
// prologue-stage + {sync; issue stage(next); compute(cur)} -> one barrier per
// K-step, staging latency hidden under MFMA (T3-minimum).
// EPI: 0=+bias (bf16)  1=+bias+fp32 resid (bf16)  2=gelu+bf16 resid (FP32)
//      3=QKV scatter: q (PRE-SCALED by 0.125*log2e), k -> [B,H,S,64];
//        v -> TRANSPOSED [B,H,64,S]
// ---------------------------------------------------------------------------
template <int EPI>
__global__ __launch_bounds__(256)
void gemm_bt(const bf16* __restrict__ A, const bf16* __restrict__ Bt,
             const float* __restrict__ bias0, const float* __restrict__ bias1,
             const float* __restrict__ bias2, const void* __restrict__ residv,
             void* __restrict__ C0v, bf16* __restrict__ C1, bf16* __restrict__ C2v,
             int M, int N, int K) {
  __shared__ bf16 As[2][128 * 32];
  __shared__ bf16 Bs[2][128 * 32];
  const int t = threadIdx.x;
  const int wave = t >> 6, lane = t & 63, quad = lane >> 4, ln = lane & 15;
  const int m0 = blockIdx.y * 128, n0 = blockIdx.x * 128;
  const int wm = (wave >> 1) * 64, wn = (wave & 1) * 64;

  v4f acc[4][4];
#pragma unroll
  for (int i = 0; i < 4; i++)
#pragma unroll
    for (int j = 0; j < 4; j++) acc[i][j] = v4f{0.f, 0.f, 0.f, 0.f};

  const int e0 = t * 8, e1 = t * 8 + 2048;
  const int ra0 = e0 >> 5, ca0 = e0 & 31, ra1 = e1 >> 5, ca1 = e1 & 31;
  const bf16* Ab = A + (long)m0 * K;
  const bf16* Bb = Bt + (long)n0 * K;

  // prologue: stage tile 0 into buffer 0
  load_lds16(Ab + (long)ra0 * K + ca0, &As[0][e0]);
  load_lds16(Ab + (long)ra1 * K + ca1, &As[0][e1]);
  load_lds16(Bb + (long)ra0 * K + ca0, &Bs[0][e0]);
  load_lds16(Bb + (long)ra1 * K + ca1, &Bs[0][e1]);

  int cur = 0;
  for (int k0 = 0; k0 < K; k0 += 32) {
    __syncthreads();  // buf[cur] staged; all waves done reading buf[cur^1]
    if (k0 + 32 < K) {
      const int kn = k0 + 32, nb = cur ^ 1;
      load_lds16(Ab + (long)ra0 * K + kn + ca0, &As[nb][e0]);
      load_lds16(Ab + (long)ra1 * K + kn + ca1, &As[nb][e1]);
      load_lds16(Bb + (long)ra0 * K + kn + ca0, &Bs[nb][e0]);
      load_lds16(Bb + (long)ra1 * K + kn + ca1, &Bs[nb][e1]);
    }
    v8s af[4], bfr[4];
#pragma unroll
    for (int mi = 0; mi < 4; mi++)
      af[mi] = *(const v8s*)&As[cur][(wm + mi * 16 + ln) * 32 + quad * 8];
#pragma unroll
    for (int ni = 0; ni < 4; ni++)
      bfr[ni] = *(const v8s*)&Bs[cur][(wn + ni * 16 + ln) * 32 + quad * 8];
#pragma unroll
    for (int mi = 0; mi < 4; mi++)
#pragma unroll
      for (int ni = 0; ni < 4; ni++)
        acc[mi][ni] = mfma16x16x32(af[mi], bfr[ni], acc[mi][ni]);
    cur ^= 1;
  }

#pragma unroll
  for (int ni = 0; ni < 4; ni++) {
    const int col = n0 + wn + ni * 16 + ln;
    if (EPI == 3) {
      const int proj = col >> 10, w = col & 1023;
      const float* bp = proj == 0 ? bias0 : (proj == 1 ? bias1 : bias2);
      const float bb = bp[w];
      const int hidx = w >> 6, hd = w & 63;
      if (proj == 2) {
        // v transposed: [b*16+h][hd][2048], ushort4-packed along s
#pragma unroll
        for (int mi = 0; mi < 4; mi++) {
          const int row0 = m0 + wm + mi * 16 + quad * 4;
          const int b_ = row0 >> 11, s = row0 & 2047;
          ushort4 pk;
          pk.x = b2u(finz(acc[mi][ni][0] + bb, 1e4f));
          pk.y = b2u(finz(acc[mi][ni][1] + bb, 1e4f));
          pk.z = b2u(finz(acc[mi][ni][2] + bb, 1e4f));
          pk.w = b2u(finz(acc[mi][ni][3] + bb, 1e4f));
          *(ushort4*)((ushort*)C2v +
                      (((long)(b_ * 16 + hidx)) * 64 + hd) * 2048 + s) = pk;
        }
      } else {
        bf16* op = proj == 0 ? (bf16*)C0v : C1;
        const float sc = proj == 0 ? 0.18033688f : 1.0f;  // 0.125*log2(e)
#pragma unroll
        for (int mi = 0; mi < 4; mi++)
#pragma unroll
          for (int r = 0; r < 4; r++) {
            const int row = m0 + wm + mi * 16 + quad * 4 + r;
            const int b_ = row >> 11, s = row & 2047;
            op[(((long)(b_ * 16 + hidx)) * 2048 + s) * 64 + hd] =
                f2b(finz((acc[mi][ni][r] + bb) * sc, 1e4f));
          }
      }
    } else {
      const float bb = bias0[col];
#pragma unroll
      for (int mi = 0; mi < 4; mi++)
#pragma unroll
        for (int r = 0; r < 4; r++) {
          const int row = m0 + wm + mi * 16 + quad * 4 + r;
          float vv = acc[mi][ni][r] + bb;
          if (EPI == 2) {
            vv = gelu_exact(vv);
            vv += b2f(((const bf16*)residv)[(long)row * N + col]);
            ((float*)C0v)[(long)row * N + col] = finz(vv, 1e5f);
          } else {
            if (EPI == 1) vv += ((const float*)residv)[(long)row * N + col];
            const float sent = EPI == 0 ? 4e4f : 2e4f;
            ((bf16*)C0v)[(long)row * N + col] = f2b(finz(vv, sent));
          }
        }
    }
  }
}

// ---------------------------------------------------------------------------
// GEMM 64x64-tile variant for skinny outputs (N=1024): 4 waves, 2x2 subtiles,
// low VGPR -> 8 blocks/CU. DOUBLE-BUFFERED LDS, one barrier per K-step.
// EPI: 1=+bias+fp32 resid (bf16 out)  2=gelu+bf16 resid (FP32 out)
// ---------------------------------------------------------------------------
template <int EPI>
__global__ __launch_bounds__(256, 8)
void gemm_bt64(const bf16* __restrict__ A, const bf16* __restrict__ Bt,
               const float* __restrict__ bias0, const void* __restrict__ residv,
               void* __restrict__ C0v, int M, int N, int K) {
  __shared__ bf16 As[2][64 * 32];
  __shared__ bf16 Bs[2][64 * 32];
  const int t = threadIdx.x;
  const int wave = t >> 6, lane = t & 63, quad = lane >> 4, ln = lane & 15;
  const int m0 = blockIdx.y * 64, n0 = blockIdx.x * 64;
  const int wm = (wave >> 1) * 32, wn = (wave & 1) * 32;

  v4f acc[2][2];
#pragma unroll
  for (int i = 0; i < 2; i++)
#pragma unroll
    for (int j = 0; j < 2; j++) acc[i][j] = v4f{0.f, 0.f, 0.f, 0.f};

  const int ra = t >> 2, ca = (t & 3) * 8;      // 64 rows x 32 cols, 16B/lane
  const bf16* Ab = A + (long)(m0 + ra) * K + ca;
  const bf16* Bb = Bt + (long)(n0 + ra) * K + ca;
  const int eo = ra * 32 + ca;                  // == element offset t*8

  // prologue: stage tile 0 into buffer 0
  load_lds16(Ab, &As[0][eo]);
  load_lds16(Bb, &Bs[0][eo]);

  int cur = 0;
  for (int k0 = 0; k0 < K; k0 += 32) {
    __syncthreads();  // buf[cur] staged; all waves done reading buf[cur^1]
    if (k0 + 32 < K) {
      const int nb = cur ^ 1;
      load_lds16(Ab + k0 + 32, &As[nb][eo]);
      load_lds16(Bb + k0 + 32, &Bs[nb][eo]);
    }
    v8s af[2], bfr[2];
#pragma unroll
    for (int mi = 0; mi < 2; mi++)
      af[mi] = *(const v8s*)&As[cur][(wm + mi * 16 + ln) * 32 + quad * 8];
#pragma unroll
    for (int ni = 0; ni < 2; ni++)
      bfr[ni] = *(const v8s*)&Bs[cur][(wn + ni * 16 + ln) * 32 + quad * 8];
#pragma unroll
    for (int mi = 0; mi < 2; mi++)
#pragma unroll
      for (int ni = 0; ni < 2; ni++)
        acc[mi][ni] = mfma16x16x32(af[mi], bfr[ni], acc[mi][ni]);
    cur ^= 1;
  }

#pragma unroll
  for (int ni = 0; ni < 2; ni++) {
    const int col = n0 + wn + ni * 16 + ln;
    const float bb = bias0[col];
#pragma unroll
    for (int mi = 0; mi < 2; mi++)
#pragma unroll
      for (int r = 0; r < 4; r++) {
        const int row = m0 + wm + mi * 16 + quad * 4 + r;
        float vv = acc[mi][ni][r] + bb;
        if (EPI == 2) {
          vv = gelu_exact(vv);
          vv += b2f(((const bf16*)residv)[(long)row * N + col]);
          ((float*)C0v)[(long)row * N + col] = finz(vv, 1e5f);
        } else {
          vv += ((const float*)residv)[(long)row * N + col];
          ((bf16*)C0v)[(long)row * N + col] = f2b(finz(vv, 2e4f));
        }
      }
  }
}

// ---------------------------------------------------------------------------
// Flash attention v5: LDS-staged K/V + defer-max (T13) + deferred-l.
// grid 1024 blocks (16 q-blocks x 64 bh, XCD-clustered). 4 waves x 32 q-rows.
// Softmax denominator kept as PER-LANE partial (cross-quad reduce ONCE in
// epilogue, not per tile). Rescale of accO skipped when the tile max stays
// within THR=8 of the running max (P bounded by 2^8; f32 accum absorbs it).
// q,k: [B,H,S,64]; vt: [B,H,64,S]. Out: [B,S,D] bf16.
// ---------------------------------------------------------------------------
__global__ __launch_bounds__(256, 4)
void attn_kernel(const bf16* __restrict__ q, const bf16* __restrict__ k,
                 const bf16* __restrict__ vt, bf16* __restrict__ o) {
  __shared__ bf16 Ks[2][64 * 64];
  __shared__ bf16 Vs[2][64 * 64];
  const int t = threadIdx.x, wave = t >> 6, lane = t & 63;
  const int quad = lane >> 4, ln = lane & 15;
  const int id = blockIdx.x;
  const int bh = ((id & 7) << 3) | ((id >> 3) >> 4);  // 8 consecutive bh/XCD
  const int qb = (id >> 3) & 15;
  const int q0 = qb * 128 + wave * 32;
  const long base = (long)bh * (2048 * 64);

  // Q as B-operand frags (register-resident)
  v8s qf[2][2];
#pragma unroll
  for (int mi = 0; mi < 2; mi++)
#pragma unroll
    for (int kc = 0; kc < 2; kc++)
      qf[mi][kc] = *(const v8s*)(q + base + (long)(q0 + mi * 16 + ln) * 64 +
                                 kc * 32 + quad * 8);

  v4f accO[2][4];  // [mi][nh]: O^T tile, col=ln (q-row), row=quad*4+r (hd)
  float m2[2], lp[2];  // lp: PER-LANE partial denominator (this lane's keys)
#pragma unroll
  for (int mi = 0; mi < 2; mi++) {
#pragma unroll
    for (int nh = 0; nh < 4; nh++) accO[mi][nh] = v4f{0.f, 0.f, 0.f, 0.f};
    m2[mi] = -1e30f;
    lp[mi] = 0.f;
  }

  // staging offsets (loop-invariant). Linear LDS off; inverse-swizzled src.
  const int o0 = t * 16, o1 = t * 16 + 4096;
  const int ks0 = o0 ^ (((o0 >> 7) & 7) << 4);
  const int ks1 = o1 ^ (((o1 >> 7) & 7) << 4);
  const int h0 = o0 >> 7, h1 = o1 >> 7;
  const int vs0 = h0 * 4096 + ((o0 ^ ((h0 & 7) << 4)) & 127);
  const int vs1 = h1 * 4096 + ((o1 ^ ((h1 & 7) << 4)) & 127);
  const char* kgb = (const char*)(k + base);
  const char* vgb = (const char*)(vt + base);

  // prologue: stage tile 0 into buffer 0
  {
    char* kl = (char*)&Ks[0][0];
    char* vl = (char*)&Vs[0][0];
    load_lds16(kgb + ks0, kl + o0);
    load_lds16(kgb + ks1, kl + o1);
    load_lds16(vgb + vs0, vl + o0);
    load_lds16(vgb + vs1, vl + o1);
  }

  for (int it = 0; it < 32; ++it) {
    const int bf = it & 1;
    __syncthreads();  // staging(bf) drained; all waves done reading bf^1
    if (it + 1 < 32) {
      const char* kg = kgb + (long)(it + 1) * (64 * 128);  // 8KB per K-tile
      const char* vg = vgb + (long)(it + 1) * 128;         // 64 keys * 2B
      char* kl = (char*)&Ks[bf ^ 1][0];
      char* vl = (char*)&Vs[bf ^ 1][0];
      load_lds16(kg + ks0, kl + o0);
      load_lds16(kg + ks1, kl + o1);
      load_lds16(vg + vs0, vl + o0);
      load_lds16(vg + vs1, vl + o1);
    }
    const char* Kb = (const char*)&Ks[bf][0];
    const char* Vb = (const char*)&Vs[bf][0];

    // S^T tiles: st[mi][ni] at lane: key = ni*16+quad*4+r, qrow = mi*16+ln
    v4f st[2][4];
    __builtin_amdgcn_s_setprio(1);
#pragma unroll
    for (int ni = 0; ni < 4; ni++) {
      const int r = ni * 16 + ln;
      const int sw = (r & 7) << 4;
      v8s k0 = *(const v8s*)(Kb + ((r * 128 + quad * 16) ^ sw));
      v8s k1 = *(const v8s*)(Kb + ((r * 128 + 64 + quad * 16) ^ sw));
#pragma unroll
      for (int mi = 0; mi < 2; mi++) {
        v4f z = v4f{0.f, 0.f, 0.f, 0.f};
        z = mfma16x16x32(k0, qf[mi][0], z);
        st[mi][ni] = mfma16x16x32(k1, qf[mi][1], z);
      }
    }
    __builtin_amdgcn_s_setprio(0);

    // online softmax (defer-max, per-lane l) -> P^T packed into x16 B-frags
    v4s pf[2][4];
#pragma unroll
    for (int mi = 0; mi < 2; mi++) {
      // max as a tree (max3-fusable)
      float a0 = fmaxf(fmaxf(st[mi][0][0], st[mi][0][1]),
                       fmaxf(st[mi][0][2], st[mi][0][3]));
      float a1 = fmaxf(fmaxf(st[mi][1][0], st[mi][1][1]),
                       fmaxf(st[mi][1][2], st[mi][1][3]));
      float a2 = fmaxf(fmaxf(st[mi][2][0], st[mi][2][1]),
                       fmaxf(st[mi][2][2], st[mi][2][3]));
      float a3 = fmaxf(fmaxf(st[mi][3][0], st[mi][3][1]),
                       fmaxf(st[mi][3][2], st[mi][3][3]));
      float mx = fmaxf(fmaxf(a0, a1), fmaxf(a2, a3));
      mx = fmaxf(mx, __shfl_xor(mx, 16));
      mx = fmaxf(mx, __shfl_xor(mx, 32));
      const float mo = m2[mi];
      if (!__all(mx <= mo + 8.0f)) {  // T13: rescale only when max grew >THR
        const float mn = fmaxf(mo, mx);
        const float al = fexp2(mo - mn);
        m2[mi] = mn;
        lp[mi] *= al;
#pragma unroll
        for (int nh = 0; nh < 4; nh++)
#pragma unroll
          for (int r = 0; r < 4; r++) accO[mi][nh][r] *= al;
      }
      const float mu = m2[mi];
      float rs = 0.f;
#pragma unroll
      for (int ni = 0; ni < 4; ni++) {
        v4s p4;
#pragma unroll
        for (int r = 0; r < 4; r++) {
          float p = fexp2(st[mi][ni][r] - mu);
          rs += p;
          p4[r] = (short)b2u(p);
        }
        pf[mi][ni] = p4;
      }
      lp[mi] += rs;  // per-lane partial; cross-quad reduce deferred to epilogue
    }

    // O^T += V^T . P^T  (A = V^T frag from LDS, B = P^T frag)
    __builtin_amdgcn_s_setprio(1);
#pragma unroll
    for (int nh = 0; nh < 4; nh++) {
      const int row = nh * 16 + ln;
      const int sw = (row & 7) << 4;
#pragma unroll
      for (int ni = 0; ni < 4; ni++) {
        v4s vv = *(const v4s*)(Vb + ((row * 128 + ni * 32 + quad * 8) ^ sw));
#pragma unroll
        for (int mi = 0; mi < 2; mi++)
          accO[mi][nh] = mfma16x16x16(vv, pf[mi][ni], accO[mi][nh]);
      }
    }
    __builtin_amdgcn_s_setprio(0);
  }

  // epilogue: reduce per-lane l across quads, then write O
  const int b_ = bh >> 4, h_ = bh & 15;
#pragma unroll
  for (int mi = 0; mi < 2; mi++) {
    float lr = lp[mi];
    lr += __shfl_xor(lr, 16);
    lr += __shfl_xor(lr, 32);
    const float inv = 1.0f / lr;
    const int s = q0 + mi * 16 + ln;
#pragma unroll
    for (int nh = 0; nh < 4; nh++) {
      ushort4 pk;
      pk.x = b2u(finz(accO[mi][nh][0] * inv, 5000.f));
      pk.y = b2u(finz(accO[mi][nh][1] * inv, 5000.f));
      pk.z = b2u(finz(accO[mi][nh][2] * inv, 5000.f));
      pk.w = b2u(finz(accO[mi][nh][3] * inv, 5000.f));
      *(ushort4*)((ushort*)o + ((long)(b_ * 2048 + s)) * 1024 + h_ * 64 +
                  nh * 16 + quad * 4) = pk;
    }
  }
}

// ---------------------------------------------------------------------------
extern "C" void kernel_launch(void* const* d_in, const int* in_sizes, int n_in,
                              void* d_out, int out_size, void* d_ws,
                              size_t ws_size, hipStream_t stream) {
  const float* x   = (const float*)d_in[0];
  const float* Wq  = (const float*)d_in[1];
  const float* bq  = (const float*)d_in[2];
  const float* Wk  = (const float*)d_in[3];
  const float* bk  = (const float*)d_in[4];
  const float* Wv  = (const float*)d_in[5];
  const float* bv  = (const float*)d_in[6];
  const float* Wo  = (const float*)d_in[7];
  const float* bo  = (const float*)d_in[8];
  const float* W1  = (const float*)d_in[9];
  const float* b1  = (const float*)d_in[10];
  const float* W2  = (const float*)d_in[11];
  const float* b2  = (const float*)d_in[12];
  const float* g1  = (const float*)d_in[13];
  const float* be1 = (const float*)d_in[14];
  const float* g2  = (const float*)d_in[15];
  const float* be2 = (const float*)d_in[16];
  float* out = (float*)d_out;

  const size_t MB = 1024 * 1024;
  if (ws_size < 104 * MB) return;
  char* W = (char*)d_ws;
  bf16* wqt = (bf16*)(W + 0 * MB);
  bf16* wkt = (bf16*)(W + 2 * MB);
  bf16* wvt = (bf16*)(W + 4 * MB);
  bf16* wot = (bf16*)(W + 6 * MB);
  bf16* h   = (bf16*)(W + 8 * MB);    // LN1 out; later LN2 out (16MB)
  bf16* qb  = (bf16*)(W + 24 * MB);   // dead after attn
  bf16* kb  = (bf16*)(W + 40 * MB);   // dead after attn
  bf16* vb  = (bf16*)(W + 56 * MB);   // v TRANSPOSED [B,H,64,S]; dead after attn
  bf16* ao  = (bf16*)(W + 72 * MB);   // dead after Wo-gemm
  bf16* x1  = (bf16*)(W + 88 * MB);   // live to end (16MB, ends 104)
  bf16* w1t = (bf16*)(W + 24 * MB);   // after attn (qb slot), 24-32
  bf16* w2t = (bf16*)(W + 32 * MB);   // 32-40
  bf16* tbc = (bf16*)(W + 40 * MB);   // FFN mid chunk [4096][4096] = 32MB, 40-72

  repack_qkv<<<4096, 256, 0, stream>>>(Wq, wqt);
  repack_qkv<<<4096, 256, 0, stream>>>(Wk, wkt);
  repack_qkv<<<4096, 256, 0, stream>>>(Wv, wvt);
  transpose_f2b<<<dim3(32, 32), 256, 0, stream>>>(Wo, wot, 1024, 1024);

  // 1) h = LN1(x)
  ln_kernel<float><<<8192, 256, 0, stream>>>(x, g1, be1, h);
  // 2) q,k,v = h @ Wqkv + b  (q scaled; q,k -> [B,H,S,64]; v -> [B,H,64,S])
  gemm_bt<3><<<dim3(24, 64), 256, 0, stream>>>(h, wqt, bq, bk, bv, nullptr,
                                               qb, kb, vb, 8192, 3072, 1024);
  // 3) flash attention -> ao [B,S,D]
  attn_kernel<<<dim3(1024), 256, 0, stream>>>(qb, kb, vb, ao);
  // 4) x1 = x + ao @ Wo + bo  (64x64 tiles -> 2048 blocks, 8/CU)
  gemm_bt64<1><<<dim3(16, 128), 256, 0, stream>>>(ao, wot, bo, x, x1,
                                                  8192, 1024, 1024);
  transpose_f2b<<<dim3(128, 32), 256, 0, stream>>>(W1, w1t, 1024, 4096);
  transpose_f2b<<<dim3(32, 128), 256, 0, stream>>>(W2, w2t, 4096, 1024);
  // 5) h2 = LN2(x1)
  ln_kernel<bf16><<<8192, 256, 0, stream>>>(x1, g2, be2, h);
  // 6/7) FFN, M-chunked (2 x 4096 rows; tbc 32MB at 40-72, clear of x1@88-104)
  for (int c = 0; c < 2; c++) {
    const long moff = (long)c * 4096 * 1024;
    gemm_bt<0><<<dim3(32, 32), 256, 0, stream>>>(h + moff, w1t, b1, nullptr,
                                                 nullptr, nullptr, tbc, nullptr,
                                                 nullptr, 4096, 4096, 1024);
    gemm_bt64<2><<<dim3(16, 64), 256, 0, stream>>>(tbc, w2t, b2, x1 + moff,
                                                   out + moff, 4096, 1024, 4096);
  }
}

// Round 8
// 521.821 us; speedup vs baseline: 1.5078x; 1.2441x over previous
//
#include <hip/hip_runtime.h>
#include <hip/hip_bf16.h>
#include <cmath>

typedef __hip_bfloat16 bf16;
typedef float v4f __attribute__((ext_vector_type(4)));
typedef short v8s __attribute__((ext_vector_type(8)));   // 8 x bf16 bits
typedef short v4s __attribute__((ext_vector_type(4)));   // 4 x bf16 bits

__device__ __forceinline__ void load_lds16(const void* g, void* l) {
  __builtin_amdgcn_global_load_lds(
      (const __attribute__((address_space(1))) char*)g,
      (__attribute__((address_space(3))) char*)l, 16, 0, 0);
}
__device__ __forceinline__ v4f mfma16x16x32(v8s a, v8s b, v4f c) {
  return __builtin_amdgcn_mfma_f32_16x16x32_bf16(a, b, c, 0, 0, 0);
}
__device__ __forceinline__ v4f mfma16x16x16(v4s a, v4s b, v4f c) {
#if __has_builtin(__builtin_amdgcn_mfma_f32_16x16x16_bf16)
  return __builtin_amdgcn_mfma_f32_16x16x16_bf16(a, b, c, 0, 0, 0);
#elif __has_builtin(__builtin_amdgcn_mfma_f32_16x16x16bf16_1k)
  return __builtin_amdgcn_mfma_f32_16x16x16bf16_1k(a, b, c, 0, 0, 0);
#else
  v4f d;
  asm("v_mfma_f32_16x16x16_bf16 %0, %1, %2, %3"
      : "=v"(d) : "v"(a), "v"(b), "v"(c));
  return d;
#endif
}
__device__ __forceinline__ float b2f(bf16 x) { return __bfloat162float(x); }
__device__ __forceinline__ bf16 f2b(float x) { return __float2bfloat16(x); }
__device__ __forceinline__ ushort b2u(float x) {
  bf16 h = f2b(x);
  return *(ushort*)&h;
}
__device__ __forceinline__ float fexp2(float x) {
#if __has_builtin(__builtin_amdgcn_exp2f)
  return __builtin_amdgcn_exp2f(x);
#else
  return exp2f(x);
#endif
}
__device__ __forceinline__ float gelu_exact(float x) {
  return 0.5f * x * (1.0f + erff(x * 0.70710678118654752f));
}
__device__ __forceinline__ float finz(float v, float sent) {
  return __builtin_isfinite(v) ? v : sent;
}
__device__ __forceinline__ float u2f(ushort u) {
  return __uint_as_float(((unsigned)u) << 16);
}
__device__ __forceinline__ float4 load4f(const float* p) {
  return *(const float4*)p;
}
__device__ __forceinline__ float4 load4f(const bf16* p) {
  ushort4 u = *(const ushort4*)p;
  return make_float4(u2f(u.x), u2f(u.y), u2f(u.z), u2f(u.w));
}

// ---------------------------------------------------------------------------
// LayerNorm: one block per row of 1024, fp32 stats, bf16 out.
// ---------------------------------------------------------------------------
template <typename TI>
__global__ __launch_bounds__(256)
void ln_kernel(const TI* __restrict__ x, const float* __restrict__ g,
               const float* __restrict__ b, bf16* __restrict__ out) {
  __shared__ float red[8];
  __shared__ float stat[2];
  const int row = blockIdx.x, t = threadIdx.x;
  const int wave = t >> 6, lane = t & 63;
  float4 v = load4f(x + (long)row * 1024 + t * 4);
  float s = v.x + v.y + v.z + v.w;
  float s2 = v.x * v.x + v.y * v.y + v.z * v.z + v.w * v.w;
#pragma unroll
  for (int off = 32; off > 0; off >>= 1) {
    s += __shfl_down(s, off);
    s2 += __shfl_down(s2, off);
  }
  if (lane == 0) { red[wave * 2] = s; red[wave * 2 + 1] = s2; }
  __syncthreads();
  if (t == 0) {
    float S = red[0] + red[2] + red[4] + red[6];
    float S2 = red[1] + red[3] + red[5] + red[7];
    float mean = S * (1.0f / 1024.0f);
    float var = S2 * (1.0f / 1024.0f) - mean * mean;
    stat[0] = mean;
    stat[1] = rsqrtf(var + 1e-5f);
  }
  __syncthreads();
  const float mean = stat[0], rs = stat[1];
  bf16* orow = out + (long)row * 1024;
  const int c = t * 4;
  float4 gg = *(const float4*)(g + c);
  float4 bb = *(const float4*)(b + c);
  orow[c + 0] = f2b(finz((v.x - mean) * rs * gg.x + bb.x, 3000.f));
  orow[c + 1] = f2b(finz((v.y - mean) * rs * gg.y + bb.y, 3000.f));
  orow[c + 2] = f2b(finz((v.z - mean) * rs * gg.z + bb.z, 3000.f));
  orow[c + 3] = f2b(finz((v.w - mean) * rs * gg.w + bb.w, 3000.f));
}

// ---------------------------------------------------------------------------
// Repack Wq/Wk/Wv fp32 [H=16, D=1024, HD=64] -> bf16 Wt[n=h*64+kk][d]
// ---------------------------------------------------------------------------
__global__ __launch_bounds__(256)
void repack_qkv(const float* __restrict__ w, bf16* __restrict__ wt) {
  long i = (long)blockIdx.x * 256 + threadIdx.x;
  int n = (int)(i >> 10), d = (int)(i & 1023);
  int h = n >> 6, kk = n & 63;
  wt[i] = f2b(w[((long)h * 1024 + d) * 64 + kk]);
}

// ---------------------------------------------------------------------------
// Plain fp32 -> bf16 cast (layout-preserving), float4-vectorized.
// Grid MUST cover nelem/1024 blocks (256 thr x 4 elem).
// ---------------------------------------------------------------------------
__global__ __launch_bounds__(256)
void cast_f2b(const float* __restrict__ in, bf16* __restrict__ out) {
  long i = ((long)blockIdx.x * 256 + threadIdx.x) * 4;
  float4 v = *(const float4*)(in + i);
  ushort4 pk;
  pk.x = b2u(v.x); pk.y = b2u(v.y); pk.z = b2u(v.z); pk.w = b2u(v.w);
  *(ushort4*)((ushort*)out + i) = pk;
}

// ---------------------------------------------------------------------------
// Fused FFN bias: bf[e] = b2[e] + sum_f b1[f] * W2[f][e]   (W2: [4096][1024])
// one block per e; deterministic tree reduce.
// ---------------------------------------------------------------------------
__global__ __launch_bounds__(256)
void ffn_bias(const float* __restrict__ b1, const float* __restrict__ W2,
              const float* __restrict__ b2, float* __restrict__ bfo) {
  __shared__ float red[4];
  const int e = blockIdx.x, t = threadIdx.x;
  float s = 0.f;
#pragma unroll
  for (int j = 0; j < 16; j++) {
    const int f = t + j * 256;
    s += b1[f] * W2[(long)f * 1024 + e];
  }
#pragma unroll
  for (int off = 32; off > 0; off >>= 1) s += __shfl_down(s, off);
  if ((t & 63) == 0) red[t >> 6] = s;
  __syncthreads();
  if (t == 0) bfo[e] = b2[e] + red[0] + red[1] + red[2] + red[3];
}

// ---------------------------------------------------------------------------
// Tiled transpose fp32 -> bf16: out[c*R + r] = in[r*C + c]
// ---------------------------------------------------------------------------
__global__ __launch_bounds__(256)
void transpose_f2b(const float* __restrict__ in, bf16* __restrict__ out,
                   int R, int C) {
  __shared__ float tile[32][33];
  const int tx = threadIdx.x & 31, ty = threadIdx.x >> 5;
  const int r0 = blockIdx.y * 32, c0 = blockIdx.x * 32;
#pragma unroll
  for (int i = ty; i < 32; i += 8) tile[i][tx] = in[(long)(r0 + i) * C + c0 + tx];
  __syncthreads();
#pragma unroll
  for (int i = ty; i < 32; i += 8)
    out[(long)(c0 + i) * R + r0 + tx] = f2b(tile[tx][i]);
}

// ---------------------------------------------------------------------------
// GEMM C[M,N] = A[M,K] @ Bt[N,K]^T (128x128, BK=32, double-buffered LDS).
// EPI: 0=+bias (bf16)  1=+bias+fp32 resid (bf16)  2=gelu+bf16 resid (FP32)
//      3=QKV scatter: q (PRE-SCALED by 0.125*log2e), k -> [B,H,S,64];
//        v -> TRANSPOSED [B,H,64,S]
// ---------------------------------------------------------------------------
template <int EPI>
__global__ __launch_bounds__(256)
void gemm_bt(const bf16* __restrict__ A, const bf16* __restrict__ Bt,
             const float* __restrict__ bias0, const float* __restrict__ bias1,
             const float* __restrict__ bias2, const void* __restrict__ residv,
             void* __restrict__ C0v, bf16* __restrict__ C1, bf16* __restrict__ C2v,
             int M, int N, int K) {
  __shared__ bf16 As[2][128 * 32];
  __shared__ bf16 Bs[2][128 * 32];
  const int t = threadIdx.x;
  const int wave = t >> 6, lane = t & 63, quad = lane >> 4, ln = lane & 15;
  const int m0 = blockIdx.y * 128, n0 = blockIdx.x * 128;
  const int wm = (wave >> 1) * 64, wn = (wave & 1) * 64;

  v4f acc[4][4];
#pragma unroll
  for (int i = 0; i < 4; i++)
#pragma unroll
    for (int j = 0; j < 4; j++) acc[i][j] = v4f{0.f, 0.f, 0.f, 0.f};

  const int e0 = t * 8, e1 = t * 8 + 2048;
  const int ra0 = e0 >> 5, ca0 = e0 & 31, ra1 = e1 >> 5, ca1 = e1 & 31;
  const bf16* Ab = A + (long)m0 * K;
  const bf16* Bb = Bt + (long)n0 * K;

  // prologue: stage tile 0 into buffer 0
  load_lds16(Ab + (long)ra0 * K + ca0, &As[0][e0]);
  load_lds16(Ab + (long)ra1 * K + ca1, &As[0][e1]);
  load_lds16(Bb + (long)ra0 * K + ca0, &Bs[0][e0]);
  load_lds16(Bb + (long)ra1 * K + ca1, &Bs[0][e1]);

  int cur = 0;
  for (int k0 = 0; k0 < K; k0 += 32) {
    __syncthreads();  // buf[cur] staged; all waves done reading buf[cur^1]
    if (k0 + 32 < K) {
      const int kn = k0 + 32, nb = cur ^ 1;
      load_lds16(Ab + (long)ra0 * K + kn + ca0, &As[nb][e0]);
      load_lds16(Ab + (long)ra1 * K + kn + ca1, &As[nb][e1]);
      load_lds16(Bb + (long)ra0 * K + kn + ca0, &Bs[nb][e0]);
      load_lds16(Bb + (long)ra1 * K + kn + ca1, &Bs[nb][e1]);
    }
    v8s af[4], bfr[4];
#pragma unroll
    for (int mi = 0; mi < 4; mi++)
      af[mi] = *(const v8s*)&As[cur][(wm + mi * 16 + ln) * 32 + quad * 8];
#pragma unroll
    for (int ni = 0; ni < 4; ni++)
      bfr[ni] = *(const v8s*)&Bs[cur][(wn + ni * 16 + ln) * 32 + quad * 8];
#pragma unroll
    for (int mi = 0; mi < 4; mi++)
#pragma unroll
      for (int ni = 0; ni < 4; ni++)
        acc[mi][ni] = mfma16x16x32(af[mi], bfr[ni], acc[mi][ni]);
    cur ^= 1;
  }

#pragma unroll
  for (int ni = 0; ni < 4; ni++) {
    const int col = n0 + wn + ni * 16 + ln;
    if (EPI == 3) {
      const int proj = col >> 10, w = col & 1023;
      const float* bp = proj == 0 ? bias0 : (proj == 1 ? bias1 : bias2);
      const float bb = bp[w];
      const int hidx = w >> 6, hd = w & 63;
      if (proj == 2) {
        // v transposed: [b*16+h][hd][2048], ushort4-packed along s
#pragma unroll
        for (int mi = 0; mi < 4; mi++) {
          const int row0 = m0 + wm + mi * 16 + quad * 4;
          const int b_ = row0 >> 11, s = row0 & 2047;
          ushort4 pk;
          pk.x = b2u(finz(acc[mi][ni][0] + bb, 1e4f));
          pk.y = b2u(finz(acc[mi][ni][1] + bb, 1e4f));
          pk.z = b2u(finz(acc[mi][ni][2] + bb, 1e4f));
          pk.w = b2u(finz(acc[mi][ni][3] + bb, 1e4f));
          *(ushort4*)((ushort*)C2v +
                      (((long)(b_ * 16 + hidx)) * 64 + hd) * 2048 + s) = pk;
        }
      } else {
        bf16* op = proj == 0 ? (bf16*)C0v : C1;
        const float sc = proj == 0 ? 0.18033688f : 1.0f;  // 0.125*log2(e)
#pragma unroll
        for (int mi = 0; mi < 4; mi++)
#pragma unroll
          for (int r = 0; r < 4; r++) {
            const int row = m0 + wm + mi * 16 + quad * 4 + r;
            const int b_ = row >> 11, s = row & 2047;
            op[(((long)(b_ * 16 + hidx)) * 2048 + s) * 64 + hd] =
                f2b(finz((acc[mi][ni][r] + bb) * sc, 1e4f));
          }
      }
    } else {
      const float bb = bias0[col];
#pragma unroll
      for (int mi = 0; mi < 4; mi++)
#pragma unroll
        for (int r = 0; r < 4; r++) {
          const int row = m0 + wm + mi * 16 + quad * 4 + r;
          float vv = acc[mi][ni][r] + bb;
          if (EPI == 2) {
            vv = gelu_exact(vv);
            vv += b2f(((const bf16*)residv)[(long)row * N + col]);
            ((float*)C0v)[(long)row * N + col] = finz(vv, 1e5f);
          } else {
            if (EPI == 1) vv += ((const float*)residv)[(long)row * N + col];
            const float sent = EPI == 0 ? 4e4f : 2e4f;
            ((bf16*)C0v)[(long)row * N + col] = f2b(finz(vv, sent));
          }
        }
    }
  }
}

// ---------------------------------------------------------------------------
// GEMM 64x64-tile variant for skinny outputs (N=1024): 4 waves, 2x2 subtiles,
// low VGPR -> 8 blocks/CU. Double-buffered LDS, one barrier per K-step.
// EPI: 0=plain bf16 store (no bias/resid)
//      1=+bias+fp32 resid (bf16 out)  2=gelu+bf16 resid (FP32 out)
// ---------------------------------------------------------------------------
template <int EPI>
__global__ __launch_bounds__(256, 8)
void gemm_bt64(const bf16* __restrict__ A, const bf16* __restrict__ Bt,
               const float* __restrict__ bias0, const void* __restrict__ residv,
               void* __restrict__ C0v, int M, int N, int K) {
  __shared__ bf16 As[2][64 * 32];
  __shared__ bf16 Bs[2][64 * 32];
  const int t = threadIdx.x;
  const int wave = t >> 6, lane = t & 63, quad = lane >> 4, ln = lane & 15;
  const int m0 = blockIdx.y * 64, n0 = blockIdx.x * 64;
  const int wm = (wave >> 1) * 32, wn = (wave & 1) * 32;

  v4f acc[2][2];
#pragma unroll
  for (int i = 0; i < 2; i++)
#pragma unroll
    for (int j = 0; j < 2; j++) acc[i][j] = v4f{0.f, 0.f, 0.f, 0.f};

  const int ra = t >> 2, ca = (t & 3) * 8;      // 64 rows x 32 cols, 16B/lane
  const bf16* Ab = A + (long)(m0 + ra) * K + ca;
  const bf16* Bb = Bt + (long)(n0 + ra) * K + ca;
  const int eo = ra * 32 + ca;                  // == element offset t*8

  // prologue: stage tile 0 into buffer 0
  load_lds16(Ab, &As[0][eo]);
  load_lds16(Bb, &Bs[0][eo]);

  int cur = 0;
  for (int k0 = 0; k0 < K; k0 += 32) {
    __syncthreads();  // buf[cur] staged; all waves done reading buf[cur^1]
    if (k0 + 32 < K) {
      const int nb = cur ^ 1;
      load_lds16(Ab + k0 + 32, &As[nb][eo]);
      load_lds16(Bb + k0 + 32, &Bs[nb][eo]);
    }
    v8s af[2], bfr[2];
#pragma unroll
    for (int mi = 0; mi < 2; mi++)
      af[mi] = *(const v8s*)&As[cur][(wm + mi * 16 + ln) * 32 + quad * 8];
#pragma unroll
    for (int ni = 0; ni < 2; ni++)
      bfr[ni] = *(const v8s*)&Bs[cur][(wn + ni * 16 + ln) * 32 + quad * 8];
#pragma unroll
    for (int mi = 0; mi < 2; mi++)
#pragma unroll
      for (int ni = 0; ni < 2; ni++)
        acc[mi][ni] = mfma16x16x32(af[mi], bfr[ni], acc[mi][ni]);
    cur ^= 1;
  }

#pragma unroll
  for (int ni = 0; ni < 2; ni++) {
    const int col = n0 + wn + ni * 16 + ln;
    float bb = 0.f;
    if (EPI != 0) bb = bias0[col];
#pragma unroll
    for (int mi = 0; mi < 2; mi++)
#pragma unroll
      for (int r = 0; r < 4; r++) {
        const int row = m0 + wm + mi * 16 + quad * 4 + r;
        float vv = acc[mi][ni][r] + bb;
        if (EPI == 2) {
          vv = gelu_exact(vv);
          vv += b2f(((const bf16*)residv)[(long)row * N + col]);
          ((float*)C0v)[(long)row * N + col] = finz(vv, 1e5f);
        } else if (EPI == 1) {
          vv += ((const float*)residv)[(long)row * N + col];
          ((bf16*)C0v)[(long)row * N + col] = f2b(finz(vv, 2e4f));
        } else {
          ((bf16*)C0v)[(long)row * N + col] = f2b(finz(vv, 2e4f));
        }
      }
  }
}

// ---------------------------------------------------------------------------
// Flash attention v5: LDS-staged K/V + defer-max (T13) + deferred-l.
// grid 1024 blocks (16 q-blocks x 64 bh, XCD-clustered). 4 waves x 32 q-rows.
// q,k: [B,H,S,64]; vt: [B,H,64,S]. Out: [B,S,D] bf16.
// ---------------------------------------------------------------------------
__global__ __launch_bounds__(256, 4)
void attn_kernel(const bf16* __restrict__ q, const bf16* __restrict__ k,
                 const bf16* __restrict__ vt, bf16* __restrict__ o) {
  __shared__ bf16 Ks[2][64 * 64];
  __shared__ bf16 Vs[2][64 * 64];
  const int t = threadIdx.x, wave = t >> 6, lane = t & 63;
  const int quad = lane >> 4, ln = lane & 15;
  const int id = blockIdx.x;
  const int bh = ((id & 7) << 3) | ((id >> 3) >> 4);  // 8 consecutive bh/XCD
  const int qb = (id >> 3) & 15;
  const int q0 = qb * 128 + wave * 32;
  const long base = (long)bh * (2048 * 64);

  // Q as B-operand frags (register-resident)
  v8s qf[2][2];
#pragma unroll
  for (int mi = 0; mi < 2; mi++)
#pragma unroll
    for (int kc = 0; kc < 2; kc++)
      qf[mi][kc] = *(const v8s*)(q + base + (long)(q0 + mi * 16 + ln) * 64 +
                                 kc * 32 + quad * 8);

  v4f accO[2][4];  // [mi][nh]: O^T tile, col=ln (q-row), row=quad*4+r (hd)
  float m2[2], lp[2];  // lp: PER-LANE partial denominator
#pragma unroll
  for (int mi = 0; mi < 2; mi++) {
#pragma unroll
    for (int nh = 0; nh < 4; nh++) accO[mi][nh] = v4f{0.f, 0.f, 0.f, 0.f};
    m2[mi] = -1e30f;
    lp[mi] = 0.f;
  }

  // staging offsets (loop-invariant). Linear LDS off; inverse-swizzled src.
  const int o0 = t * 16, o1 = t * 16 + 4096;
  const int ks0 = o0 ^ (((o0 >> 7) & 7) << 4);
  const int ks1 = o1 ^ (((o1 >> 7) & 7) << 4);
  const int h0 = o0 >> 7, h1 = o1 >> 7;
  const int vs0 = h0 * 4096 + ((o0 ^ ((h0 & 7) << 4)) & 127);
  const int vs1 = h1 * 4096 + ((o1 ^ ((h1 & 7) << 4)) & 127);
  const char* kgb = (const char*)(k + base);
  const char* vgb = (const char*)(vt + base);

  // prologue: stage tile 0 into buffer 0
  {
    char* kl = (char*)&Ks[0][0];
    char* vl = (char*)&Vs[0][0];
    load_lds16(kgb + ks0, kl + o0);
    load_lds16(kgb + ks1, kl + o1);
    load_lds16(vgb + vs0, vl + o0);
    load_lds16(vgb + vs1, vl + o1);
  }

  for (int it = 0; it < 32; ++it) {
    const int bf = it & 1;
    __syncthreads();  // staging(bf) drained; all waves done reading bf^1
    if (it + 1 < 32) {
      const char* kg = kgb + (long)(it + 1) * (64 * 128);  // 8KB per K-tile
      const char* vg = vgb + (long)(it + 1) * 128;         // 64 keys * 2B
      char* kl = (char*)&Ks[bf ^ 1][0];
      char* vl = (char*)&Vs[bf ^ 1][0];
      load_lds16(kg + ks0, kl + o0);
      load_lds16(kg + ks1, kl + o1);
      load_lds16(vg + vs0, vl + o0);
      load_lds16(vg + vs1, vl + o1);
    }
    const char* Kb = (const char*)&Ks[bf][0];
    const char* Vb = (const char*)&Vs[bf][0];

    // S^T tiles: st[mi][ni] at lane: key = ni*16+quad*4+r, qrow = mi*16+ln
    v4f st[2][4];
    __builtin_amdgcn_s_setprio(1);
#pragma unroll
    for (int ni = 0; ni < 4; ni++) {
      const int r = ni * 16 + ln;
      const int sw = (r & 7) << 4;
      v8s k0 = *(const v8s*)(Kb + ((r * 128 + quad * 16) ^ sw));
      v8s k1 = *(const v8s*)(Kb + ((r * 128 + 64 + quad * 16) ^ sw));
#pragma unroll
      for (int mi = 0; mi < 2; mi++) {
        v4f z = v4f{0.f, 0.f, 0.f, 0.f};
        z = mfma16x16x32(k0, qf[mi][0], z);
        st[mi][ni] = mfma16x16x32(k1, qf[mi][1], z);
      }
    }
    __builtin_amdgcn_s_setprio(0);

    // online softmax (defer-max, per-lane l) -> P^T packed into x16 B-frags
    v4s pf[2][4];
#pragma unroll
    for (int mi = 0; mi < 2; mi++) {
      float a0 = fmaxf(fmaxf(st[mi][0][0], st[mi][0][1]),
                       fmaxf(st[mi][0][2], st[mi][0][3]));
      float a1 = fmaxf(fmaxf(st[mi][1][0], st[mi][1][1]),
                       fmaxf(st[mi][1][2], st[mi][1][3]));
      float a2 = fmaxf(fmaxf(st[mi][2][0], st[mi][2][1]),
                       fmaxf(st[mi][2][2], st[mi][2][3]));
      float a3 = fmaxf(fmaxf(st[mi][3][0], st[mi][3][1]),
                       fmaxf(st[mi][3][2], st[mi][3][3]));
      float mx = fmaxf(fmaxf(a0, a1), fmaxf(a2, a3));
      mx = fmaxf(mx, __shfl_xor(mx, 16));
      mx = fmaxf(mx, __shfl_xor(mx, 32));
      const float mo = m2[mi];
      if (!__all(mx <= mo + 8.0f)) {  // T13: rescale only when max grew >THR
        const float mn = fmaxf(mo, mx);
        const float al = fexp2(mo - mn);
        m2[mi] = mn;
        lp[mi] *= al;
#pragma unroll
        for (int nh = 0; nh < 4; nh++)
#pragma unroll
          for (int r = 0; r < 4; r++) accO[mi][nh][r] *= al;
      }
      const float mu = m2[mi];
      float rs = 0.f;
#pragma unroll
      for (int ni = 0; ni < 4; ni++) {
        v4s p4;
#pragma unroll
        for (int r = 0; r < 4; r++) {
          float p = fexp2(st[mi][ni][r] - mu);
          rs += p;
          p4[r] = (short)b2u(p);
        }
        pf[mi][ni] = p4;
      }
      lp[mi] += rs;  // per-lane partial; cross-quad reduce in epilogue
    }

    // O^T += V^T . P^T  (A = V^T frag from LDS, B = P^T frag)
    __builtin_amdgcn_s_setprio(1);
#pragma unroll
    for (int nh = 0; nh < 4; nh++) {
      const int row = nh * 16 + ln;
      const int sw = (row & 7) << 4;
#pragma unroll
      for (int ni = 0; ni < 4; ni++) {
        v4s vv = *(const v4s*)(Vb + ((row * 128 + ni * 32 + quad * 8) ^ sw));
#pragma unroll
        for (int mi = 0; mi < 2; mi++)
          accO[mi][nh] = mfma16x16x16(vv, pf[mi][ni], accO[mi][nh]);
      }
    }
    __builtin_amdgcn_s_setprio(0);
  }

  // epilogue: reduce per-lane l across quads, then write O
  const int b_ = bh >> 4, h_ = bh & 15;
#pragma unroll
  for (int mi = 0; mi < 2; mi++) {
    float lr = lp[mi];
    lr += __shfl_xor(lr, 16);
    lr += __shfl_xor(lr, 32);
    const float inv = 1.0f / lr;
    const int s = q0 + mi * 16 + ln;
#pragma unroll
    for (int nh = 0; nh < 4; nh++) {
      ushort4 pk;
      pk.x = b2u(finz(accO[mi][nh][0] * inv, 5000.f));
      pk.y = b2u(finz(accO[mi][nh][1] * inv, 5000.f));
      pk.z = b2u(finz(accO[mi][nh][2] * inv, 5000.f));
      pk.w = b2u(finz(accO[mi][nh][3] * inv, 5000.f));
      *(ushort4*)((ushort*)o + ((long)(b_ * 2048 + s)) * 1024 + h_ * 64 +
                  nh * 16 + quad * 4) = pk;
    }
  }
}

// ---------------------------------------------------------------------------
extern "C" void kernel_launch(void* const* d_in, const int* in_sizes, int n_in,
                              void* d_out, int out_size, void* d_ws,
                              size_t ws_size, hipStream_t stream) {
  const float* x   = (const float*)d_in[0];
  const float* Wq  = (const float*)d_in[1];
  const float* bq  = (const float*)d_in[2];
  const float* Wk  = (const float*)d_in[3];
  const float* bk  = (const float*)d_in[4];
  const float* Wv  = (const float*)d_in[5];
  const float* bv  = (const float*)d_in[6];
  const float* Wo  = (const float*)d_in[7];
  const float* bo  = (const float*)d_in[8];
  const float* W1  = (const float*)d_in[9];
  const float* b1  = (const float*)d_in[10];
  const float* W2  = (const float*)d_in[11];
  const float* b2  = (const float*)d_in[12];
  const float* g1  = (const float*)d_in[13];
  const float* be1 = (const float*)d_in[14];
  const float* g2  = (const float*)d_in[15];
  const float* be2 = (const float*)d_in[16];
  float* out = (float*)d_out;

  const size_t MB = 1024 * 1024;
  if (ws_size < 104 * MB) return;
  char* W = (char*)d_ws;
  bf16* wqt = (bf16*)(W + 0 * MB);
  bf16* wkt = (bf16*)(W + 2 * MB);
  bf16* wvt = (bf16*)(W + 4 * MB);
  bf16* wot = (bf16*)(W + 6 * MB);
  bf16* h   = (bf16*)(W + 8 * MB);    // LN1 out; later LN2 out (16MB, 8-24)
  bf16* qb  = (bf16*)(W + 24 * MB);   // dead after attn
  bf16* kb  = (bf16*)(W + 40 * MB);   // dead after attn
  bf16* vb  = (bf16*)(W + 56 * MB);   // v TRANSPOSED; dead after attn
  bf16* ao  = (bf16*)(W + 72 * MB);   // dead after Wo-gemm
  bf16* x1  = (bf16*)(W + 88 * MB);   // live to end (16MB, 88-104)
  bf16* w1b = (bf16*)(W + 24 * MB);   // after attn (qb slot): W1 bf16 8MB, 24-32
  bf16* w2t = (bf16*)(W + 32 * MB);   // W2^T bf16 [1024][4096] 8MB, 32-40
  bf16* wft = (bf16*)(W + 40 * MB);   // Wf^T = (W1@W2)^T bf16 [1024][1024], 40-42
  float* bfb = (float*)(W + 44 * MB); // fused FFN bias [1024] fp32

  repack_qkv<<<4096, 256, 0, stream>>>(Wq, wqt);
  repack_qkv<<<4096, 256, 0, stream>>>(Wk, wkt);
  repack_qkv<<<4096, 256, 0, stream>>>(Wv, wvt);
  transpose_f2b<<<dim3(32, 32), 256, 0, stream>>>(Wo, wot, 1024, 1024);

  // 1) h = LN1(x)
  ln_kernel<float><<<8192, 256, 0, stream>>>(x, g1, be1, h);
  // 2) q,k,v = h @ Wqkv + b  (q scaled; q,k -> [B,H,S,64]; v -> [B,H,64,S])
  gemm_bt<3><<<dim3(24, 64), 256, 0, stream>>>(h, wqt, bq, bk, bv, nullptr,
                                               qb, kb, vb, 8192, 3072, 1024);
  // 3) flash attention -> ao [B,S,D]
  attn_kernel<<<dim3(1024), 256, 0, stream>>>(qb, kb, vb, ao);
  // 4) x1 = x + ao @ Wo + bo  (64x64 tiles -> 2048 blocks, 8/CU)
  gemm_bt64<1><<<dim3(16, 128), 256, 0, stream>>>(ao, wot, bo, x, x1,
                                                  8192, 1024, 1024);
  // --- FFN reparameterization: no nonlinearity between W1 and W2, so
  //     gelu((h2@W1 + b1)@W2 + b2) == gelu(h2@(W1@W2) + (b1@W2 + b2)).
  //     Precompute WfT[e][d] = sum_f W2T[e][f]*W1[d][f] and bf. ---
  // W1 has 1024*4096 = 4M elems -> 4096 blocks x 1024 elems/block.  (BUG FIX:
  // was 1024 blocks = only 1/4 of W1 cast; rest was stale qb data.)
  cast_f2b<<<4096, 256, 0, stream>>>(W1, w1b);
  transpose_f2b<<<dim3(32, 128), 256, 0, stream>>>(W2, w2t, 4096, 1024);
  gemm_bt64<0><<<dim3(16, 16), 256, 0, stream>>>(w2t, w1b, nullptr, nullptr,
                                                 wft, 1024, 1024, 4096);
  ffn_bias<<<1024, 256, 0, stream>>>(b1, W2, b2, bfb);
  // 5) h2 = LN2(x1)
  ln_kernel<bf16><<<8192, 256, 0, stream>>>(x1, g2, be2, h);
  // 6) out = x1 + gelu(h2 @ Wf + bf)   (single 17.2 GF gemm, 2048 blocks)
  gemm_bt64<2><<<dim3(16, 128), 256, 0, stream>>>(h, wft, bfb, x1, out,
                                                  8192, 1024, 1024);
}

// Round 9
// 515.217 us; speedup vs baseline: 1.5272x; 1.0128x over previous
//
#include <hip/hip_runtime.h>
#include <hip/hip_bf16.h>
#include <cmath>

typedef __hip_bfloat16 bf16;
typedef float v4f __attribute__((ext_vector_type(4)));
typedef short v8s __attribute__((ext_vector_type(8)));   // 8 x bf16 bits
typedef short v4s __attribute__((ext_vector_type(4)));   // 4 x bf16 bits

__device__ __forceinline__ void load_lds16(const void* g, void* l) {
  __builtin_amdgcn_global_load_lds(
      (const __attribute__((address_space(1))) char*)g,
      (__attribute__((address_space(3))) char*)l, 16, 0, 0);
}
__device__ __forceinline__ v4f mfma16x16x32(v8s a, v8s b, v4f c) {
  return __builtin_amdgcn_mfma_f32_16x16x32_bf16(a, b, c, 0, 0, 0);
}
__device__ __forceinline__ v4f mfma16x16x16(v4s a, v4s b, v4f c) {
#if __has_builtin(__builtin_amdgcn_mfma_f32_16x16x16_bf16)
  return __builtin_amdgcn_mfma_f32_16x16x16_bf16(a, b, c, 0, 0, 0);
#elif __has_builtin(__builtin_amdgcn_mfma_f32_16x16x16bf16_1k)
  return __builtin_amdgcn_mfma_f32_16x16x16bf16_1k(a, b, c, 0, 0, 0);
#else
  v4f d;
  asm("v_mfma_f32_16x16x16_bf16 %0, %1, %2, %3"
      : "=v"(d) : "v"(a), "v"(b), "v"(c));
  return d;
#endif
}
__device__ __forceinline__ float b2f(bf16 x) { return __bfloat162float(x); }
__device__ __forceinline__ bf16 f2b(float x) { return __float2bfloat16(x); }
__device__ __forceinline__ ushort b2u(float x) {
  bf16 h = f2b(x);
  return *(ushort*)&h;
}
__device__ __forceinline__ float fexp2(float x) {
#if __has_builtin(__builtin_amdgcn_exp2f)
  return __builtin_amdgcn_exp2f(x);
#else
  return exp2f(x);
#endif
}
__device__ __forceinline__ float gelu_exact(float x) {
  return 0.5f * x * (1.0f + erff(x * 0.70710678118654752f));
}
__device__ __forceinline__ float finz(float v, float sent) {
  return __builtin_isfinite(v) ? v : sent;
}
__device__ __forceinline__ float u2f(ushort u) {
  return __uint_as_float(((unsigned)u) << 16);
}
__device__ __forceinline__ float4 load4f(const float* p) {
  return *(const float4*)p;
}
__device__ __forceinline__ float4 load4f(const bf16* p) {
  ushort4 u = *(const ushort4*)p;
  return make_float4(u2f(u.x), u2f(u.y), u2f(u.z), u2f(u.w));
}

// ---------------------------------------------------------------------------
// LayerNorm: one block per row of 1024, fp32 stats, bf16 out.
// ---------------------------------------------------------------------------
template <typename TI>
__global__ __launch_bounds__(256)
void ln_kernel(const TI* __restrict__ x, const float* __restrict__ g,
               const float* __restrict__ b, bf16* __restrict__ out) {
  __shared__ float red[8];
  __shared__ float stat[2];
  const int row = blockIdx.x, t = threadIdx.x;
  const int wave = t >> 6, lane = t & 63;
  float4 v = load4f(x + (long)row * 1024 + t * 4);
  float s = v.x + v.y + v.z + v.w;
  float s2 = v.x * v.x + v.y * v.y + v.z * v.z + v.w * v.w;
#pragma unroll
  for (int off = 32; off > 0; off >>= 1) {
    s += __shfl_down(s, off);
    s2 += __shfl_down(s2, off);
  }
  if (lane == 0) { red[wave * 2] = s; red[wave * 2 + 1] = s2; }
  __syncthreads();
  if (t == 0) {
    float S = red[0] + red[2] + red[4] + red[6];
    float S2 = red[1] + red[3] + red[5] + red[7];
    float mean = S * (1.0f / 1024.0f);
    float var = S2 * (1.0f / 1024.0f) - mean * mean;
    stat[0] = mean;
    stat[1] = rsqrtf(var + 1e-5f);
  }
  __syncthreads();
  const float mean = stat[0], rs = stat[1];
  bf16* orow = out + (long)row * 1024;
  const int c = t * 4;
  float4 gg = *(const float4*)(g + c);
  float4 bb = *(const float4*)(b + c);
  orow[c + 0] = f2b(finz((v.x - mean) * rs * gg.x + bb.x, 3000.f));
  orow[c + 1] = f2b(finz((v.y - mean) * rs * gg.y + bb.y, 3000.f));
  orow[c + 2] = f2b(finz((v.z - mean) * rs * gg.z + bb.z, 3000.f));
  orow[c + 3] = f2b(finz((v.w - mean) * rs * gg.w + bb.w, 3000.f));
}

// ---------------------------------------------------------------------------
// Repack Wq/Wk/Wv fp32 [H=16, D=1024, HD=64] -> bf16 Wt[n=h*64+kk][d]
// ---------------------------------------------------------------------------
__global__ __launch_bounds__(256)
void repack_qkv(const float* __restrict__ w, bf16* __restrict__ wt) {
  long i = (long)blockIdx.x * 256 + threadIdx.x;
  int n = (int)(i >> 10), d = (int)(i & 1023);
  int h = n >> 6, kk = n & 63;
  wt[i] = f2b(w[((long)h * 1024 + d) * 64 + kk]);
}

// ---------------------------------------------------------------------------
// Plain fp32 -> bf16 cast (layout-preserving), float4-vectorized.
// Grid MUST cover nelem/1024 blocks (256 thr x 4 elem).
// ---------------------------------------------------------------------------
__global__ __launch_bounds__(256)
void cast_f2b(const float* __restrict__ in, bf16* __restrict__ out) {
  long i = ((long)blockIdx.x * 256 + threadIdx.x) * 4;
  float4 v = *(const float4*)(in + i);
  ushort4 pk;
  pk.x = b2u(v.x); pk.y = b2u(v.y); pk.z = b2u(v.z); pk.w = b2u(v.w);
  *(ushort4*)((ushort*)out + i) = pk;
}

// ---------------------------------------------------------------------------
// Fused FFN bias: bf[e] = b2[e] + sum_f b1[f] * W2[f][e]   (W2: [4096][1024])
// one block per e; deterministic tree reduce.
// ---------------------------------------------------------------------------
__global__ __launch_bounds__(256)
void ffn_bias(const float* __restrict__ b1, const float* __restrict__ W2,
              const float* __restrict__ b2, float* __restrict__ bfo) {
  __shared__ float red[4];
  const int e = blockIdx.x, t = threadIdx.x;
  float s = 0.f;
#pragma unroll
  for (int j = 0; j < 16; j++) {
    const int f = t + j * 256;
    s += b1[f] * W2[(long)f * 1024 + e];
  }
#pragma unroll
  for (int off = 32; off > 0; off >>= 1) s += __shfl_down(s, off);
  if ((t & 63) == 0) red[t >> 6] = s;
  __syncthreads();
  if (t == 0) bfo[e] = b2[e] + red[0] + red[1] + red[2] + red[3];
}

// ---------------------------------------------------------------------------
// Tiled transpose fp32 -> bf16: out[c*R + r] = in[r*C + c]
// ---------------------------------------------------------------------------
__global__ __launch_bounds__(256)
void transpose_f2b(const float* __restrict__ in, bf16* __restrict__ out,
                   int R, int C) {
  __shared__ float tile[32][33];
  const int tx = threadIdx.x & 31, ty = threadIdx.x >> 5;
  const int r0 = blockIdx.y * 32, c0 = blockIdx.x * 32;
#pragma unroll
  for (int i = ty; i < 32; i += 8) tile[i][tx] = in[(long)(r0 + i) * C + c0 + tx];
  __syncthreads();
#pragma unroll
  for (int i = ty; i < 32; i += 8)
    out[(long)(c0 + i) * R + r0 + tx] = f2b(tile[tx][i]);
}

// ---------------------------------------------------------------------------
// GEMM C[M,N] = A[M,K] @ Bt[N,K]^T (128x128, BK=32, double-buffered LDS).
// EPI: 0=+bias (bf16)  1=+bias+fp32 resid (bf16)  2=gelu+bf16 resid (FP32)
//      3=QKV scatter: q (PRE-SCALED by 0.125*log2e), k -> [B,H,S,64];
//        v -> TRANSPOSED [B,H,64,S]
// ---------------------------------------------------------------------------
template <int EPI>
__global__ __launch_bounds__(256)
void gemm_bt(const bf16* __restrict__ A, const bf16* __restrict__ Bt,
             const float* __restrict__ bias0, const float* __restrict__ bias1,
             const float* __restrict__ bias2, const void* __restrict__ residv,
             void* __restrict__ C0v, bf16* __restrict__ C1, bf16* __restrict__ C2v,
             int M, int N, int K) {
  __shared__ bf16 As[2][128 * 32];
  __shared__ bf16 Bs[2][128 * 32];
  const int t = threadIdx.x;
  const int wave = t >> 6, lane = t & 63, quad = lane >> 4, ln = lane & 15;
  const int m0 = blockIdx.y * 128, n0 = blockIdx.x * 128;
  const int wm = (wave >> 1) * 64, wn = (wave & 1) * 64;

  v4f acc[4][4];
#pragma unroll
  for (int i = 0; i < 4; i++)
#pragma unroll
    for (int j = 0; j < 4; j++) acc[i][j] = v4f{0.f, 0.f, 0.f, 0.f};

  const int e0 = t * 8, e1 = t * 8 + 2048;
  const int ra0 = e0 >> 5, ca0 = e0 & 31, ra1 = e1 >> 5, ca1 = e1 & 31;
  const bf16* Ab = A + (long)m0 * K;
  const bf16* Bb = Bt + (long)n0 * K;

  // prologue: stage tile 0 into buffer 0
  load_lds16(Ab + (long)ra0 * K + ca0, &As[0][e0]);
  load_lds16(Ab + (long)ra1 * K + ca1, &As[0][e1]);
  load_lds16(Bb + (long)ra0 * K + ca0, &Bs[0][e0]);
  load_lds16(Bb + (long)ra1 * K + ca1, &Bs[0][e1]);

  int cur = 0;
  for (int k0 = 0; k0 < K; k0 += 32) {
    __syncthreads();  // buf[cur] staged; all waves done reading buf[cur^1]
    if (k0 + 32 < K) {
      const int kn = k0 + 32, nb = cur ^ 1;
      load_lds16(Ab + (long)ra0 * K + kn + ca0, &As[nb][e0]);
      load_lds16(Ab + (long)ra1 * K + kn + ca1, &As[nb][e1]);
      load_lds16(Bb + (long)ra0 * K + kn + ca0, &Bs[nb][e0]);
      load_lds16(Bb + (long)ra1 * K + kn + ca1, &Bs[nb][e1]);
    }
    v8s af[4], bfr[4];
#pragma unroll
    for (int mi = 0; mi < 4; mi++)
      af[mi] = *(const v8s*)&As[cur][(wm + mi * 16 + ln) * 32 + quad * 8];
#pragma unroll
    for (int ni = 0; ni < 4; ni++)
      bfr[ni] = *(const v8s*)&Bs[cur][(wn + ni * 16 + ln) * 32 + quad * 8];
#pragma unroll
    for (int mi = 0; mi < 4; mi++)
#pragma unroll
      for (int ni = 0; ni < 4; ni++)
        acc[mi][ni] = mfma16x16x32(af[mi], bfr[ni], acc[mi][ni]);
    cur ^= 1;
  }

#pragma unroll
  for (int ni = 0; ni < 4; ni++) {
    const int col = n0 + wn + ni * 16 + ln;
    if (EPI == 3) {
      const int proj = col >> 10, w = col & 1023;
      const float* bp = proj == 0 ? bias0 : (proj == 1 ? bias1 : bias2);
      const float bb = bp[w];
      const int hidx = w >> 6, hd = w & 63;
      if (proj == 2) {
        // v transposed: [b*16+h][hd][2048], ushort4-packed along s
#pragma unroll
        for (int mi = 0; mi < 4; mi++) {
          const int row0 = m0 + wm + mi * 16 + quad * 4;
          const int b_ = row0 >> 11, s = row0 & 2047;
          ushort4 pk;
          pk.x = b2u(finz(acc[mi][ni][0] + bb, 1e4f));
          pk.y = b2u(finz(acc[mi][ni][1] + bb, 1e4f));
          pk.z = b2u(finz(acc[mi][ni][2] + bb, 1e4f));
          pk.w = b2u(finz(acc[mi][ni][3] + bb, 1e4f));
          *(ushort4*)((ushort*)C2v +
                      (((long)(b_ * 16 + hidx)) * 64 + hd) * 2048 + s) = pk;
        }
      } else {
        bf16* op = proj == 0 ? (bf16*)C0v : C1;
        const float sc = proj == 0 ? 0.18033688f : 1.0f;  // 0.125*log2(e)
#pragma unroll
        for (int mi = 0; mi < 4; mi++)
#pragma unroll
          for (int r = 0; r < 4; r++) {
            const int row = m0 + wm + mi * 16 + quad * 4 + r;
            const int b_ = row >> 11, s = row & 2047;
            op[(((long)(b_ * 16 + hidx)) * 2048 + s) * 64 + hd] =
                f2b(finz((acc[mi][ni][r] + bb) * sc, 1e4f));
          }
      }
    } else {
      const float bb = bias0[col];
#pragma unroll
      for (int mi = 0; mi < 4; mi++)
#pragma unroll
        for (int r = 0; r < 4; r++) {
          const int row = m0 + wm + mi * 16 + quad * 4 + r;
          float vv = acc[mi][ni][r] + bb;
          if (EPI == 2) {
            vv = gelu_exact(vv);
            vv += b2f(((const bf16*)residv)[(long)row * N + col]);
            ((float*)C0v)[(long)row * N + col] = finz(vv, 1e5f);
          } else {
            if (EPI == 1) vv += ((const float*)residv)[(long)row * N + col];
            const float sent = EPI == 0 ? 4e4f : 2e4f;
            ((bf16*)C0v)[(long)row * N + col] = f2b(finz(vv, sent));
          }
        }
    }
  }
}

// ---------------------------------------------------------------------------
// GEMM 64x64-tile variant for skinny outputs (N=1024): 4 waves, 2x2 subtiles,
// low VGPR -> 8 blocks/CU. Double-buffered LDS, one barrier per K-step.
// EPI: 0=plain bf16 store (no bias/resid)
//      1=+bias+fp32 resid (bf16 out)  2=gelu+bf16 resid (FP32 out)
// ---------------------------------------------------------------------------
template <int EPI>
__global__ __launch_bounds__(256, 8)
void gemm_bt64(const bf16* __restrict__ A, const bf16* __restrict__ Bt,
               const float* __restrict__ bias0, const void* __restrict__ residv,
               void* __restrict__ C0v, int M, int N, int K) {
  __shared__ bf16 As[2][64 * 32];
  __shared__ bf16 Bs[2][64 * 32];
  const int t = threadIdx.x;
  const int wave = t >> 6, lane = t & 63, quad = lane >> 4, ln = lane & 15;
  const int m0 = blockIdx.y * 64, n0 = blockIdx.x * 64;
  const int wm = (wave >> 1) * 32, wn = (wave & 1) * 32;

  v4f acc[2][2];
#pragma unroll
  for (int i = 0; i < 2; i++)
#pragma unroll
    for (int j = 0; j < 2; j++) acc[i][j] = v4f{0.f, 0.f, 0.f, 0.f};

  const int ra = t >> 2, ca = (t & 3) * 8;      // 64 rows x 32 cols, 16B/lane
  const bf16* Ab = A + (long)(m0 + ra) * K + ca;
  const bf16* Bb = Bt + (long)(n0 + ra) * K + ca;
  const int eo = ra * 32 + ca;                  // == element offset t*8

  // prologue: stage tile 0 into buffer 0
  load_lds16(Ab, &As[0][eo]);
  load_lds16(Bb, &Bs[0][eo]);

  int cur = 0;
  for (int k0 = 0; k0 < K; k0 += 32) {
    __syncthreads();  // buf[cur] staged; all waves done reading buf[cur^1]
    if (k0 + 32 < K) {
      const int nb = cur ^ 1;
      load_lds16(Ab + k0 + 32, &As[nb][eo]);
      load_lds16(Bb + k0 + 32, &Bs[nb][eo]);
    }
    v8s af[2], bfr[2];
#pragma unroll
    for (int mi = 0; mi < 2; mi++)
      af[mi] = *(const v8s*)&As[cur][(wm + mi * 16 + ln) * 32 + quad * 8];
#pragma unroll
    for (int ni = 0; ni < 2; ni++)
      bfr[ni] = *(const v8s*)&Bs[cur][(wn + ni * 16 + ln) * 32 + quad * 8];
#pragma unroll
    for (int mi = 0; mi < 2; mi++)
#pragma unroll
      for (int ni = 0; ni < 2; ni++)
        acc[mi][ni] = mfma16x16x32(af[mi], bfr[ni], acc[mi][ni]);
    cur ^= 1;
  }

#pragma unroll
  for (int ni = 0; ni < 2; ni++) {
    const int col = n0 + wn + ni * 16 + ln;
    float bb = 0.f;
    if (EPI != 0) bb = bias0[col];
#pragma unroll
    for (int mi = 0; mi < 2; mi++)
#pragma unroll
      for (int r = 0; r < 4; r++) {
        const int row = m0 + wm + mi * 16 + quad * 4 + r;
        float vv = acc[mi][ni][r] + bb;
        if (EPI == 2) {
          vv = gelu_exact(vv);
          vv += b2f(((const bf16*)residv)[(long)row * N + col]);
          ((float*)C0v)[(long)row * N + col] = finz(vv, 1e5f);
        } else if (EPI == 1) {
          vv += ((const float*)residv)[(long)row * N + col];
          ((bf16*)C0v)[(long)row * N + col] = f2b(finz(vv, 2e4f));
        } else {
          ((bf16*)C0v)[(long)row * N + col] = f2b(finz(vv, 2e4f));
        }
      }
  }
}

// ---------------------------------------------------------------------------
// Split-K Wf precompute: partial[z][m][n] = sum_{k in chunk z}
//   w2t[m][4096-row][koff+k] * w1b[n][koff+k], 64x64 tiles, K-chunk = 1024.
// grid (16,16,4) = 1024 blocks (vs 256 un-split: 1 blk/CU latency-bound).
// fp32 partials; reduced+cast by reduce_wf.
// ---------------------------------------------------------------------------
__global__ __launch_bounds__(256, 8)
void gemm_wf_splitk(const bf16* __restrict__ A, const bf16* __restrict__ Bt,
                    float* __restrict__ pout) {
  __shared__ bf16 As[2][64 * 32];
  __shared__ bf16 Bs[2][64 * 32];
  const int t = threadIdx.x;
  const int wave = t >> 6, lane = t & 63, quad = lane >> 4, ln = lane & 15;
  const int m0 = blockIdx.y * 64, n0 = blockIdx.x * 64;
  const long koff = (long)blockIdx.z * 1024;
  const int wm = (wave >> 1) * 32, wn = (wave & 1) * 32;

  v4f acc[2][2];
#pragma unroll
  for (int i = 0; i < 2; i++)
#pragma unroll
    for (int j = 0; j < 2; j++) acc[i][j] = v4f{0.f, 0.f, 0.f, 0.f};

  const int ra = t >> 2, ca = (t & 3) * 8;
  const bf16* Ab = A + (long)(m0 + ra) * 4096 + koff + ca;
  const bf16* Bb = Bt + (long)(n0 + ra) * 4096 + koff + ca;
  const int eo = ra * 32 + ca;

  load_lds16(Ab, &As[0][eo]);
  load_lds16(Bb, &Bs[0][eo]);

  int cur = 0;
  for (int k0 = 0; k0 < 1024; k0 += 32) {
    __syncthreads();
    if (k0 + 32 < 1024) {
      const int nb = cur ^ 1;
      load_lds16(Ab + k0 + 32, &As[nb][eo]);
      load_lds16(Bb + k0 + 32, &Bs[nb][eo]);
    }
    v8s af[2], bfr[2];
#pragma unroll
    for (int mi = 0; mi < 2; mi++)
      af[mi] = *(const v8s*)&As[cur][(wm + mi * 16 + ln) * 32 + quad * 8];
#pragma unroll
    for (int ni = 0; ni < 2; ni++)
      bfr[ni] = *(const v8s*)&Bs[cur][(wn + ni * 16 + ln) * 32 + quad * 8];
#pragma unroll
    for (int mi = 0; mi < 2; mi++)
#pragma unroll
      for (int ni = 0; ni < 2; ni++)
        acc[mi][ni] = mfma16x16x32(af[mi], bfr[ni], acc[mi][ni]);
    cur ^= 1;
  }

  float* po = pout + (long)blockIdx.z * (1024 * 1024);
#pragma unroll
  for (int ni = 0; ni < 2; ni++) {
    const int col = n0 + wn + ni * 16 + ln;
#pragma unroll
    for (int mi = 0; mi < 2; mi++)
#pragma unroll
      for (int r = 0; r < 4; r++) {
        const int row = m0 + wm + mi * 16 + quad * 4 + r;
        po[(long)row * 1024 + col] = acc[mi][ni][r];
      }
  }
}

// ---------------------------------------------------------------------------
// Reduce 4 fp32 partials -> bf16 Wf^T. 1M elems, float4-vectorized.
// ---------------------------------------------------------------------------
__global__ __launch_bounds__(256)
void reduce_wf(const float* __restrict__ p, bf16* __restrict__ wft) {
  const long i = ((long)blockIdx.x * 256 + threadIdx.x) * 4;
  float4 a = *(const float4*)(p + i);
  float4 b = *(const float4*)(p + i + 1048576);
  float4 c = *(const float4*)(p + i + 2097152);
  float4 d = *(const float4*)(p + i + 3145728);
  ushort4 pk;
  pk.x = b2u((a.x + b.x) + (c.x + d.x));
  pk.y = b2u((a.y + b.y) + (c.y + d.y));
  pk.z = b2u((a.z + b.z) + (c.z + d.z));
  pk.w = b2u((a.w + b.w) + (c.w + d.w));
  *(ushort4*)((ushort*)wft + i) = pk;
}

// ---------------------------------------------------------------------------
// Flash attention v5: LDS-staged K/V + defer-max (T13) + deferred-l.
// grid 1024 blocks (16 q-blocks x 64 bh, XCD-clustered). 4 waves x 32 q-rows.
// kv-loop unrolled x2 so buffer index bf is compile-time per copy -> LDS
// read/stage addresses are loop-invariant registers (cuts VALU addr recompute).
// q,k: [B,H,S,64]; vt: [B,H,64,S]. Out: [B,S,D] bf16.
// ---------------------------------------------------------------------------
__global__ __launch_bounds__(256, 4)
void attn_kernel(const bf16* __restrict__ q, const bf16* __restrict__ k,
                 const bf16* __restrict__ vt, bf16* __restrict__ o) {
  __shared__ bf16 Ks[2][64 * 64];
  __shared__ bf16 Vs[2][64 * 64];
  const int t = threadIdx.x, wave = t >> 6, lane = t & 63;
  const int quad = lane >> 4, ln = lane & 15;
  const int id = blockIdx.x;
  const int bh = ((id & 7) << 3) | ((id >> 3) >> 4);  // 8 consecutive bh/XCD
  const int qb = (id >> 3) & 15;
  const int q0 = qb * 128 + wave * 32;
  const long base = (long)bh * (2048 * 64);

  // Q as B-operand frags (register-resident)
  v8s qf[2][2];
#pragma unroll
  for (int mi = 0; mi < 2; mi++)
#pragma unroll
    for (int kc = 0; kc < 2; kc++)
      qf[mi][kc] = *(const v8s*)(q + base + (long)(q0 + mi * 16 + ln) * 64 +
                                 kc * 32 + quad * 8);

  v4f accO[2][4];  // [mi][nh]: O^T tile, col=ln (q-row), row=quad*4+r (hd)
  float m2[2], lp[2];  // lp: PER-LANE partial denominator
#pragma unroll
  for (int mi = 0; mi < 2; mi++) {
#pragma unroll
    for (int nh = 0; nh < 4; nh++) accO[mi][nh] = v4f{0.f, 0.f, 0.f, 0.f};
    m2[mi] = -1e30f;
    lp[mi] = 0.f;
  }

  // staging offsets (loop-invariant). Linear LDS off; inverse-swizzled src.
  const int o0 = t * 16, o1 = t * 16 + 4096;
  const int ks0 = o0 ^ (((o0 >> 7) & 7) << 4);
  const int ks1 = o1 ^ (((o1 >> 7) & 7) << 4);
  const int h0 = o0 >> 7, h1 = o1 >> 7;
  const int vs0 = h0 * 4096 + ((o0 ^ ((h0 & 7) << 4)) & 127);
  const int vs1 = h1 * 4096 + ((o1 ^ ((h1 & 7) << 4)) & 127);
  const char* kgb = (const char*)(k + base);
  const char* vgb = (const char*)(vt + base);

  // prologue: stage tile 0 into buffer 0
  {
    char* kl = (char*)&Ks[0][0];
    char* vl = (char*)&Vs[0][0];
    load_lds16(kgb + ks0, kl + o0);
    load_lds16(kgb + ks1, kl + o1);
    load_lds16(vgb + vs0, vl + o0);
    load_lds16(vgb + vs1, vl + o1);
  }

#pragma unroll 2
  for (int it = 0; it < 32; ++it) {
    const int bf = it & 1;
    __syncthreads();  // staging(bf) drained; all waves done reading bf^1
    if (it + 1 < 32) {
      const char* kg = kgb + (long)(it + 1) * (64 * 128);  // 8KB per K-tile
      const char* vg = vgb + (long)(it + 1) * 128;         // 64 keys * 2B
      char* kl = (char*)&Ks[bf ^ 1][0];
      char* vl = (char*)&Vs[bf ^ 1][0];
      load_lds16(kg + ks0, kl + o0);
      load_lds16(kg + ks1, kl + o1);
      load_lds16(vg + vs0, vl + o0);
      load_lds16(vg + vs1, vl + o1);
    }
    const char* Kb = (const char*)&Ks[bf][0];
    const char* Vb = (const char*)&Vs[bf][0];

    // S^T tiles: st[mi][ni] at lane: key = ni*16+quad*4+r, qrow = mi*16+ln
    v4f st[2][4];
    __builtin_amdgcn_s_setprio(1);
#pragma unroll
    for (int ni = 0; ni < 4; ni++) {
      const int r = ni * 16 + ln;
      const int sw = (r & 7) << 4;
      v8s k0 = *(const v8s*)(Kb + ((r * 128 + quad * 16) ^ sw));
      v8s k1 = *(const v8s*)(Kb + ((r * 128 + 64 + quad * 16) ^ sw));
#pragma unroll
      for (int mi = 0; mi < 2; mi++) {
        v4f z = v4f{0.f, 0.f, 0.f, 0.f};
        z = mfma16x16x32(k0, qf[mi][0], z);
        st[mi][ni] = mfma16x16x32(k1, qf[mi][1], z);
      }
    }
    __builtin_amdgcn_s_setprio(0);

    // online softmax (defer-max, per-lane l) -> P^T packed into x16 B-frags
    v4s pf[2][4];
#pragma unroll
    for (int mi = 0; mi < 2; mi++) {
      float a0 = fmaxf(fmaxf(st[mi][0][0], st[mi][0][1]),
                       fmaxf(st[mi][0][2], st[mi][0][3]));
      float a1 = fmaxf(fmaxf(st[mi][1][0], st[mi][1][1]),
                       fmaxf(st[mi][1][2], st[mi][1][3]));
      float a2 = fmaxf(fmaxf(st[mi][2][0], st[mi][2][1]),
                       fmaxf(st[mi][2][2], st[mi][2][3]));
      float a3 = fmaxf(fmaxf(st[mi][3][0], st[mi][3][1]),
                       fmaxf(st[mi][3][2], st[mi][3][3]));
      float mx = fmaxf(fmaxf(a0, a1), fmaxf(a2, a3));
      mx = fmaxf(mx, __shfl_xor(mx, 16));
      mx = fmaxf(mx, __shfl_xor(mx, 32));
      const float mo = m2[mi];
      if (!__all(mx <= mo + 8.0f)) {  // T13: rescale only when max grew >THR
        const float mn = fmaxf(mo, mx);
        const float al = fexp2(mo - mn);
        m2[mi] = mn;
        lp[mi] *= al;
#pragma unroll
        for (int nh = 0; nh < 4; nh++)
#pragma unroll
          for (int r = 0; r < 4; r++) accO[mi][nh][r] *= al;
      }
      const float mu = m2[mi];
      float rs = 0.f;
#pragma unroll
      for (int ni = 0; ni < 4; ni++) {
        v4s p4;
#pragma unroll
        for (int r = 0; r < 4; r++) {
          float p = fexp2(st[mi][ni][r] - mu);
          rs += p;
          p4[r] = (short)b2u(p);
        }
        pf[mi][ni] = p4;
      }
      lp[mi] += rs;  // per-lane partial; cross-quad reduce in epilogue
    }

    // O^T += V^T . P^T  (A = V^T frag from LDS, B = P^T frag)
    __builtin_amdgcn_s_setprio(1);
#pragma unroll
    for (int nh = 0; nh < 4; nh++) {
      const int row = nh * 16 + ln;
      const int sw = (row & 7) << 4;
#pragma unroll
      for (int ni = 0; ni < 4; ni++) {
        v4s vv = *(const v4s*)(Vb + ((row * 128 + ni * 32 + quad * 8) ^ sw));
#pragma unroll
        for (int mi = 0; mi < 2; mi++)
          accO[mi][nh] = mfma16x16x16(vv, pf[mi][ni], accO[mi][nh]);
      }
    }
    __builtin_amdgcn_s_setprio(0);
  }

  // epilogue: reduce per-lane l across quads, then write O
  const int b_ = bh >> 4, h_ = bh & 15;
#pragma unroll
  for (int mi = 0; mi < 2; mi++) {
    float lr = lp[mi];
    lr += __shfl_xor(lr, 16);
    lr += __shfl_xor(lr, 32);
    const float inv = 1.0f / lr;
    const int s = q0 + mi * 16 + ln;
#pragma unroll
    for (int nh = 0; nh < 4; nh++) {
      ushort4 pk;
      pk.x = b2u(finz(accO[mi][nh][0] * inv, 5000.f));
      pk.y = b2u(finz(accO[mi][nh][1] * inv, 5000.f));
      pk.z = b2u(finz(accO[mi][nh][2] * inv, 5000.f));
      pk.w = b2u(finz(accO[mi][nh][3] * inv, 5000.f));
      *(ushort4*)((ushort*)o + ((long)(b_ * 2048 + s)) * 1024 + h_ * 64 +
                  nh * 16 + quad * 4) = pk;
    }
  }
}

// ---------------------------------------------------------------------------
extern "C" void kernel_launch(void* const* d_in, const int* in_sizes, int n_in,
                              void* d_out, int out_size, void* d_ws,
                              size_t ws_size, hipStream_t stream) {
  const float* x   = (const float*)d_in[0];
  const float* Wq  = (const float*)d_in[1];
  const float* bq  = (const float*)d_in[2];
  const float* Wk  = (const float*)d_in[3];
  const float* bk  = (const float*)d_in[4];
  const float* Wv  = (const float*)d_in[5];
  const float* bv  = (const float*)d_in[6];
  const float* Wo  = (const float*)d_in[7];
  const float* bo  = (const float*)d_in[8];
  const float* W1  = (const float*)d_in[9];
  const float* b1  = (const float*)d_in[10];
  const float* W2  = (const float*)d_in[11];
  const float* b2  = (const float*)d_in[12];
  const float* g1  = (const float*)d_in[13];
  const float* be1 = (const float*)d_in[14];
  const float* g2  = (const float*)d_in[15];
  const float* be2 = (const float*)d_in[16];
  float* out = (float*)d_out;

  const size_t MB = 1024 * 1024;
  if (ws_size < 104 * MB) return;
  char* W = (char*)d_ws;
  bf16* wqt = (bf16*)(W + 0 * MB);
  bf16* wkt = (bf16*)(W + 2 * MB);
  bf16* wvt = (bf16*)(W + 4 * MB);
  bf16* wot = (bf16*)(W + 6 * MB);
  bf16* h   = (bf16*)(W + 8 * MB);    // LN1 out; later LN2 out (16MB, 8-24)
  bf16* qb  = (bf16*)(W + 24 * MB);   // dead after attn
  bf16* kb  = (bf16*)(W + 40 * MB);   // dead after attn
  bf16* vb  = (bf16*)(W + 56 * MB);   // v TRANSPOSED; dead after attn
  bf16* ao  = (bf16*)(W + 72 * MB);   // dead after Wo-gemm
  bf16* x1  = (bf16*)(W + 88 * MB);   // live to end (16MB, 88-104)
  bf16* w1b = (bf16*)(W + 24 * MB);   // after attn (qb slot): W1 bf16 8MB, 24-32
  bf16* w2t = (bf16*)(W + 32 * MB);   // W2^T bf16 [1024][4096] 8MB, 32-40
  bf16* wft = (bf16*)(W + 40 * MB);   // Wf^T bf16 [1024][1024] 2MB, 40-42
  float* bfb = (float*)(W + 44 * MB); // fused FFN bias [1024] fp32
  float* wfp = (float*)(W + 56 * MB); // Wf split-K partials [4][1024][1024] 16MB
                                      //   56-72 (vb slot, dead after attn)

  repack_qkv<<<4096, 256, 0, stream>>>(Wq, wqt);
  repack_qkv<<<4096, 256, 0, stream>>>(Wk, wkt);
  repack_qkv<<<4096, 256, 0, stream>>>(Wv, wvt);
  transpose_f2b<<<dim3(32, 32), 256, 0, stream>>>(Wo, wot, 1024, 1024);

  // 1) h = LN1(x)
  ln_kernel<float><<<8192, 256, 0, stream>>>(x, g1, be1, h);
  // 2) q,k,v = h @ Wqkv + b  (q scaled; q,k -> [B,H,S,64]; v -> [B,H,64,S])
  gemm_bt<3><<<dim3(24, 64), 256, 0, stream>>>(h, wqt, bq, bk, bv, nullptr,
                                               qb, kb, vb, 8192, 3072, 1024);
  // 3) flash attention -> ao [B,S,D]
  attn_kernel<<<dim3(1024), 256, 0, stream>>>(qb, kb, vb, ao);
  // 4) x1 = x + ao @ Wo + bo  (64x64 tiles -> 2048 blocks, 8/CU)
  gemm_bt64<1><<<dim3(16, 128), 256, 0, stream>>>(ao, wot, bo, x, x1,
                                                  8192, 1024, 1024);
  // --- FFN reparameterization: no nonlinearity between W1 and W2, so
  //     gelu((h2@W1 + b1)@W2 + b2) == gelu(h2@(W1@W2) + (b1@W2 + b2)).
  //     Wf^T computed split-K x4 (1024 blocks vs 256: was 1/CU latency-bound).
  cast_f2b<<<4096, 256, 0, stream>>>(W1, w1b);   // 4M elems = 4096 blocks
  transpose_f2b<<<dim3(32, 128), 256, 0, stream>>>(W2, w2t, 4096, 1024);
  gemm_wf_splitk<<<dim3(16, 16, 4), 256, 0, stream>>>(w2t, w1b, wfp);
  reduce_wf<<<1024, 256, 0, stream>>>(wfp, wft);
  ffn_bias<<<1024, 256, 0, stream>>>(b1, W2, b2, bfb);
  // 5) h2 = LN2(x1)
  ln_kernel<bf16><<<8192, 256, 0, stream>>>(x1, g2, be2, h);
  // 6) out = x1 + gelu(h2 @ Wf + bf)   (single 17.2 GF gemm, 2048 blocks)
  gemm_bt64<2><<<dim3(16, 128), 256, 0, stream>>>(h, wft, bfb, x1, out,
                                                  8192, 1024, 1024);
}

// Round 10
// 489.819 us; speedup vs baseline: 1.6064x; 1.0519x over previous
//
#include <hip/hip_runtime.h>
#include <hip/hip_bf16.h>
#include <cmath>

typedef __hip_bfloat16 bf16;
typedef float v4f __attribute__((ext_vector_type(4)));
typedef short v8s __attribute__((ext_vector_type(8)));   // 8 x bf16 bits
typedef short v4s __attribute__((ext_vector_type(4)));   // 4 x bf16 bits

__device__ __forceinline__ void load_lds16(const void* g, void* l) {
  __builtin_amdgcn_global_load_lds(
      (const __attribute__((address_space(1))) char*)g,
      (__attribute__((address_space(3))) char*)l, 16, 0, 0);
}
__device__ __forceinline__ v4f mfma16x16x32(v8s a, v8s b, v4f c) {
  return __builtin_amdgcn_mfma_f32_16x16x32_bf16(a, b, c, 0, 0, 0);
}
__device__ __forceinline__ v4f mfma16x16x16(v4s a, v4s b, v4f c) {
#if __has_builtin(__builtin_amdgcn_mfma_f32_16x16x16_bf16)
  return __builtin_amdgcn_mfma_f32_16x16x16_bf16(a, b, c, 0, 0, 0);
#elif __has_builtin(__builtin_amdgcn_mfma_f32_16x16x16bf16_1k)
  return __builtin_amdgcn_mfma_f32_16x16x16bf16_1k(a, b, c, 0, 0, 0);
#else
  v4f d;
  asm("v_mfma_f32_16x16x16_bf16 %0, %1, %2, %3"
      : "=v"(d) : "v"(a), "v"(b), "v"(c));
  return d;
#endif
}
__device__ __forceinline__ float b2f(bf16 x) { return __bfloat162float(x); }
__device__ __forceinline__ bf16 f2b(float x) { return __float2bfloat16(x); }
__device__ __forceinline__ ushort b2u(float x) {
  bf16 h = f2b(x);
  return *(ushort*)&h;
}
__device__ __forceinline__ float fexp2(float x) {
#if __has_builtin(__builtin_amdgcn_exp2f)
  return __builtin_amdgcn_exp2f(x);
#else
  return exp2f(x);
#endif
}
__device__ __forceinline__ float gelu_exact(float x) {
  return 0.5f * x * (1.0f + erff(x * 0.70710678118654752f));
}
__device__ __forceinline__ float finz(float v, float sent) {
  return __builtin_isfinite(v) ? v : sent;
}
__device__ __forceinline__ float u2f(ushort u) {
  return __uint_as_float(((unsigned)u) << 16);
}
__device__ __forceinline__ float4 load4f(const float* p) {
  return *(const float4*)p;
}
__device__ __forceinline__ float4 load4f(const bf16* p) {
  ushort4 u = *(const ushort4*)p;
  return make_float4(u2f(u.x), u2f(u.y), u2f(u.z), u2f(u.w));
}

// ---------------------------------------------------------------------------
// LayerNorm: one block per row of 1024, fp32 stats, bf16 out.
// ---------------------------------------------------------------------------
template <typename TI>
__global__ __launch_bounds__(256)
void ln_kernel(const TI* __restrict__ x, const float* __restrict__ g,
               const float* __restrict__ b, bf16* __restrict__ out) {
  __shared__ float red[8];
  __shared__ float stat[2];
  const int row = blockIdx.x, t = threadIdx.x;
  const int wave = t >> 6, lane = t & 63;
  float4 v = load4f(x + (long)row * 1024 + t * 4);
  float s = v.x + v.y + v.z + v.w;
  float s2 = v.x * v.x + v.y * v.y + v.z * v.z + v.w * v.w;
#pragma unroll
  for (int off = 32; off > 0; off >>= 1) {
    s += __shfl_down(s, off);
    s2 += __shfl_down(s2, off);
  }
  if (lane == 0) { red[wave * 2] = s; red[wave * 2 + 1] = s2; }
  __syncthreads();
  if (t == 0) {
    float S = red[0] + red[2] + red[4] + red[6];
    float S2 = red[1] + red[3] + red[5] + red[7];
    float mean = S * (1.0f / 1024.0f);
    float var = S2 * (1.0f / 1024.0f) - mean * mean;
    stat[0] = mean;
    stat[1] = rsqrtf(var + 1e-5f);
  }
  __syncthreads();
  const float mean = stat[0], rs = stat[1];
  bf16* orow = out + (long)row * 1024;
  const int c = t * 4;
  float4 gg = *(const float4*)(g + c);
  float4 bb = *(const float4*)(b + c);
  orow[c + 0] = f2b(finz((v.x - mean) * rs * gg.x + bb.x, 3000.f));
  orow[c + 1] = f2b(finz((v.y - mean) * rs * gg.y + bb.y, 3000.f));
  orow[c + 2] = f2b(finz((v.z - mean) * rs * gg.z + bb.z, 3000.f));
  orow[c + 3] = f2b(finz((v.w - mean) * rs * gg.w + bb.w, 3000.f));
}

// ---------------------------------------------------------------------------
// Repack Wq/Wk/Wv fp32 [H=16, D=1024, HD=64] -> bf16 Wt[n=h*64+kk][d]
// ---------------------------------------------------------------------------
__global__ __launch_bounds__(256)
void repack_qkv(const float* __restrict__ w, bf16* __restrict__ wt) {
  long i = (long)blockIdx.x * 256 + threadIdx.x;
  int n = (int)(i >> 10), d = (int)(i & 1023);
  int h = n >> 6, kk = n & 63;
  wt[i] = f2b(w[((long)h * 1024 + d) * 64 + kk]);
}

// ---------------------------------------------------------------------------
// Plain fp32 -> bf16 cast (layout-preserving), float4-vectorized.
// Grid MUST cover nelem/1024 blocks (256 thr x 4 elem).
// ---------------------------------------------------------------------------
__global__ __launch_bounds__(256)
void cast_f2b(const float* __restrict__ in, bf16* __restrict__ out) {
  long i = ((long)blockIdx.x * 256 + threadIdx.x) * 4;
  float4 v = *(const float4*)(in + i);
  ushort4 pk;
  pk.x = b2u(v.x); pk.y = b2u(v.y); pk.z = b2u(v.z); pk.w = b2u(v.w);
  *(ushort4*)((ushort*)out + i) = pk;
}

// ---------------------------------------------------------------------------
// Fused FFN bias: bf[e] = b2[e] + sum_f b1[f] * W2[f][e]   (W2: [4096][1024])
// ---------------------------------------------------------------------------
__global__ __launch_bounds__(256)
void ffn_bias(const float* __restrict__ b1, const float* __restrict__ W2,
              const float* __restrict__ b2, float* __restrict__ bfo) {
  __shared__ float red[4];
  const int e = blockIdx.x, t = threadIdx.x;
  float s = 0.f;
#pragma unroll
  for (int j = 0; j < 16; j++) {
    const int f = t + j * 256;
    s += b1[f] * W2[(long)f * 1024 + e];
  }
#pragma unroll
  for (int off = 32; off > 0; off >>= 1) s += __shfl_down(s, off);
  if ((t & 63) == 0) red[t >> 6] = s;
  __syncthreads();
  if (t == 0) bfo[e] = b2[e] + red[0] + red[1] + red[2] + red[3];
}

// ---------------------------------------------------------------------------
// Tiled transpose fp32 -> bf16: out[c*R + r] = in[r*C + c]
// ---------------------------------------------------------------------------
__global__ __launch_bounds__(256)
void transpose_f2b(const float* __restrict__ in, bf16* __restrict__ out,
                   int R, int C) {
  __shared__ float tile[32][33];
  const int tx = threadIdx.x & 31, ty = threadIdx.x >> 5;
  const int r0 = blockIdx.y * 32, c0 = blockIdx.x * 32;
#pragma unroll
  for (int i = ty; i < 32; i += 8) tile[i][tx] = in[(long)(r0 + i) * C + c0 + tx];
  __syncthreads();
#pragma unroll
  for (int i = ty; i < 32; i += 8)
    out[(long)(c0 + i) * R + r0 + tx] = f2b(tile[tx][i]);
}

// ---------------------------------------------------------------------------
// GEMM C[M,N] = A[M,K] @ Bt[N,K]^T (128x128, BK=32, double-buffered LDS).
// EPI: 0=+bias (bf16)  1=+bias+fp32 resid (bf16)  2=gelu+bf16 resid (FP32)
//      3=QKV scatter: q (PRE-SCALED by 0.125*log2e), k -> [B,H,S,64];
//        v -> TRANSPOSED [B,H,64,S]
// ---------------------------------------------------------------------------
template <int EPI>
__global__ __launch_bounds__(256)
void gemm_bt(const bf16* __restrict__ A, const bf16* __restrict__ Bt,
             const float* __restrict__ bias0, const float* __restrict__ bias1,
             const float* __restrict__ bias2, const void* __restrict__ residv,
             void* __restrict__ C0v, bf16* __restrict__ C1, bf16* __restrict__ C2v,
             int M, int N, int K) {
  __shared__ bf16 As[2][128 * 32];
  __shared__ bf16 Bs[2][128 * 32];
  const int t = threadIdx.x;
  const int wave = t >> 6, lane = t & 63, quad = lane >> 4, ln = lane & 15;
  const int m0 = blockIdx.y * 128, n0 = blockIdx.x * 128;
  const int wm = (wave >> 1) * 64, wn = (wave & 1) * 64;

  v4f acc[4][4];
#pragma unroll
  for (int i = 0; i < 4; i++)
#pragma unroll
    for (int j = 0; j < 4; j++) acc[i][j] = v4f{0.f, 0.f, 0.f, 0.f};

  const int e0 = t * 8, e1 = t * 8 + 2048;
  const int ra0 = e0 >> 5, ca0 = e0 & 31, ra1 = e1 >> 5, ca1 = e1 & 31;
  const bf16* Ab = A + (long)m0 * K;
  const bf16* Bb = Bt + (long)n0 * K;

  // prologue: stage tile 0 into buffer 0
  load_lds16(Ab + (long)ra0 * K + ca0, &As[0][e0]);
  load_lds16(Ab + (long)ra1 * K + ca1, &As[0][e1]);
  load_lds16(Bb + (long)ra0 * K + ca0, &Bs[0][e0]);
  load_lds16(Bb + (long)ra1 * K + ca1, &Bs[0][e1]);

  int cur = 0;
  for (int k0 = 0; k0 < K; k0 += 32) {
    __syncthreads();  // buf[cur] staged; all waves done reading buf[cur^1]
    if (k0 + 32 < K) {
      const int kn = k0 + 32, nb = cur ^ 1;
      load_lds16(Ab + (long)ra0 * K + kn + ca0, &As[nb][e0]);
      load_lds16(Ab + (long)ra1 * K + kn + ca1, &As[nb][e1]);
      load_lds16(Bb + (long)ra0 * K + kn + ca0, &Bs[nb][e0]);
      load_lds16(Bb + (long)ra1 * K + kn + ca1, &Bs[nb][e1]);
    }
    v8s af[4], bfr[4];
#pragma unroll
    for (int mi = 0; mi < 4; mi++)
      af[mi] = *(const v8s*)&As[cur][(wm + mi * 16 + ln) * 32 + quad * 8];
#pragma unroll
    for (int ni = 0; ni < 4; ni++)
      bfr[ni] = *(const v8s*)&Bs[cur][(wn + ni * 16 + ln) * 32 + quad * 8];
#pragma unroll
    for (int mi = 0; mi < 4; mi++)
#pragma unroll
      for (int ni = 0; ni < 4; ni++)
        acc[mi][ni] = mfma16x16x32(af[mi], bfr[ni], acc[mi][ni]);
    cur ^= 1;
  }

#pragma unroll
  for (int ni = 0; ni < 4; ni++) {
    const int col = n0 + wn + ni * 16 + ln;
    if (EPI == 3) {
      const int proj = col >> 10, w = col & 1023;
      const float* bp = proj == 0 ? bias0 : (proj == 1 ? bias1 : bias2);
      const float bb = bp[w];
      const int hidx = w >> 6, hd = w & 63;
      if (proj == 2) {
        // v transposed: [b*16+h][hd][2048], ushort4-packed along s
#pragma unroll
        for (int mi = 0; mi < 4; mi++) {
          const int row0 = m0 + wm + mi * 16 + quad * 4;
          const int b_ = row0 >> 11, s = row0 & 2047;
          ushort4 pk;
          pk.x = b2u(finz(acc[mi][ni][0] + bb, 1e4f));
          pk.y = b2u(finz(acc[mi][ni][1] + bb, 1e4f));
          pk.z = b2u(finz(acc[mi][ni][2] + bb, 1e4f));
          pk.w = b2u(finz(acc[mi][ni][3] + bb, 1e4f));
          *(ushort4*)((ushort*)C2v +
                      (((long)(b_ * 16 + hidx)) * 64 + hd) * 2048 + s) = pk;
        }
      } else {
        bf16* op = proj == 0 ? (bf16*)C0v : C1;
        const float sc = proj == 0 ? 0.18033688f : 1.0f;  // 0.125*log2(e)
#pragma unroll
        for (int mi = 0; mi < 4; mi++)
#pragma unroll
          for (int r = 0; r < 4; r++) {
            const int row = m0 + wm + mi * 16 + quad * 4 + r;
            const int b_ = row >> 11, s = row & 2047;
            op[(((long)(b_ * 16 + hidx)) * 2048 + s) * 64 + hd] =
                f2b(finz((acc[mi][ni][r] + bb) * sc, 1e4f));
          }
      }
    } else {
      const float bb = bias0[col];
#pragma unroll
      for (int mi = 0; mi < 4; mi++)
#pragma unroll
        for (int r = 0; r < 4; r++) {
          const int row = m0 + wm + mi * 16 + quad * 4 + r;
          float vv = acc[mi][ni][r] + bb;
          if (EPI == 2) {
            vv = gelu_exact(vv);
            vv += b2f(((const bf16*)residv)[(long)row * N + col]);
            ((float*)C0v)[(long)row * N + col] = finz(vv, 1e5f);
          } else {
            if (EPI == 1) vv += ((const float*)residv)[(long)row * N + col];
            const float sent = EPI == 0 ? 4e4f : 2e4f;
            ((bf16*)C0v)[(long)row * N + col] = f2b(finz(vv, sent));
          }
        }
    }
  }
}

// ---------------------------------------------------------------------------
// GEMM 128x64-tile variant for skinny outputs (N=1024): 4 waves (2Mx2N),
// per-wave 4x2 subtiles -> 8 MFMA : 6 ds_read : 3 stage per K-step (2x the
// MFMA density of the 64x64 tile). grid (N/64, M/128) = 1024 blocks = 4/CU.
// LDS 24KB dbuf. EPI: 1=+bias+fp32 resid (bf16)  2=gelu+bf16 resid (FP32)
// ---------------------------------------------------------------------------
template <int EPI>
__global__ __launch_bounds__(256, 4)
void gemm_bt12864(const bf16* __restrict__ A, const bf16* __restrict__ Bt,
                  const float* __restrict__ bias0, const void* __restrict__ residv,
                  void* __restrict__ C0v, int M, int N, int K) {
  __shared__ bf16 As[2][128 * 32];
  __shared__ bf16 Bs[2][64 * 32];
  const int t = threadIdx.x;
  const int wave = t >> 6, lane = t & 63, quad = lane >> 4, ln = lane & 15;
  const int m0 = blockIdx.y * 128, n0 = blockIdx.x * 64;
  const int wm = (wave >> 1) * 64, wn = (wave & 1) * 32;

  v4f acc[4][2];
#pragma unroll
  for (int i = 0; i < 4; i++)
#pragma unroll
    for (int j = 0; j < 2; j++) acc[i][j] = v4f{0.f, 0.f, 0.f, 0.f};

  // A: 128x32 = 512 16B-chunks, 2/thread; B: 64x32 = 256 chunks, 1/thread
  const int ea0 = t * 8, ea1 = t * 8 + 2048;
  const int raA0 = ea0 >> 5, caA0 = ea0 & 31;
  const int raA1 = ea1 >> 5, caA1 = ea1 & 31;
  const int rb = t >> 2, cb = (t & 3) * 8;
  const bf16* Ab = A + (long)m0 * K;
  const bf16* Bb = Bt + (long)(n0 + rb) * K + cb;

  load_lds16(Ab + (long)raA0 * K + caA0, &As[0][ea0]);
  load_lds16(Ab + (long)raA1 * K + caA1, &As[0][ea1]);
  load_lds16(Bb, &Bs[0][t * 8]);

  int cur = 0;
  for (int k0 = 0; k0 < K; k0 += 32) {
    __syncthreads();
    if (k0 + 32 < K) {
      const int kn = k0 + 32, nb = cur ^ 1;
      load_lds16(Ab + (long)raA0 * K + kn + caA0, &As[nb][ea0]);
      load_lds16(Ab + (long)raA1 * K + kn + caA1, &As[nb][ea1]);
      load_lds16(Bb + kn, &Bs[nb][t * 8]);
    }
    v8s af[4], bfr[2];
#pragma unroll
    for (int mi = 0; mi < 4; mi++)
      af[mi] = *(const v8s*)&As[cur][(wm + mi * 16 + ln) * 32 + quad * 8];
#pragma unroll
    for (int ni = 0; ni < 2; ni++)
      bfr[ni] = *(const v8s*)&Bs[cur][(wn + ni * 16 + ln) * 32 + quad * 8];
#pragma unroll
    for (int mi = 0; mi < 4; mi++)
#pragma unroll
      for (int ni = 0; ni < 2; ni++)
        acc[mi][ni] = mfma16x16x32(af[mi], bfr[ni], acc[mi][ni]);
    cur ^= 1;
  }

#pragma unroll
  for (int ni = 0; ni < 2; ni++) {
    const int col = n0 + wn + ni * 16 + ln;
    const float bb = bias0[col];
#pragma unroll
    for (int mi = 0; mi < 4; mi++)
#pragma unroll
      for (int r = 0; r < 4; r++) {
        const int row = m0 + wm + mi * 16 + quad * 4 + r;
        float vv = acc[mi][ni][r] + bb;
        if (EPI == 2) {
          vv = gelu_exact(vv);
          vv += b2f(((const bf16*)residv)[(long)row * N + col]);
          ((float*)C0v)[(long)row * N + col] = finz(vv, 1e5f);
        } else {
          vv += ((const float*)residv)[(long)row * N + col];
          ((bf16*)C0v)[(long)row * N + col] = f2b(finz(vv, 2e4f));
        }
      }
  }
}

// ---------------------------------------------------------------------------
// Split-K Wf precompute: partial[z] = chunk-z product, 64x64 tiles, Kc=1024.
// grid (16,16,4) = 1024 blocks. fp32 partials; reduced+cast by reduce_wf.
// ---------------------------------------------------------------------------
__global__ __launch_bounds__(256, 8)
void gemm_wf_splitk(const bf16* __restrict__ A, const bf16* __restrict__ Bt,
                    float* __restrict__ pout) {
  __shared__ bf16 As[2][64 * 32];
  __shared__ bf16 Bs[2][64 * 32];
  const int t = threadIdx.x;
  const int wave = t >> 6, lane = t & 63, quad = lane >> 4, ln = lane & 15;
  const int m0 = blockIdx.y * 64, n0 = blockIdx.x * 64;
  const long koff = (long)blockIdx.z * 1024;
  const int wm = (wave >> 1) * 32, wn = (wave & 1) * 32;

  v4f acc[2][2];
#pragma unroll
  for (int i = 0; i < 2; i++)
#pragma unroll
    for (int j = 0; j < 2; j++) acc[i][j] = v4f{0.f, 0.f, 0.f, 0.f};

  const int ra = t >> 2, ca = (t & 3) * 8;
  const bf16* Ab = A + (long)(m0 + ra) * 4096 + koff + ca;
  const bf16* Bb = Bt + (long)(n0 + ra) * 4096 + koff + ca;
  const int eo = ra * 32 + ca;

  load_lds16(Ab, &As[0][eo]);
  load_lds16(Bb, &Bs[0][eo]);

  int cur = 0;
  for (int k0 = 0; k0 < 1024; k0 += 32) {
    __syncthreads();
    if (k0 + 32 < 1024) {
      const int nb = cur ^ 1;
      load_lds16(Ab + k0 + 32, &As[nb][eo]);
      load_lds16(Bb + k0 + 32, &Bs[nb][eo]);
    }
    v8s af[2], bfr[2];
#pragma unroll
    for (int mi = 0; mi < 2; mi++)
      af[mi] = *(const v8s*)&As[cur][(wm + mi * 16 + ln) * 32 + quad * 8];
#pragma unroll
    for (int ni = 0; ni < 2; ni++)
      bfr[ni] = *(const v8s*)&Bs[cur][(wn + ni * 16 + ln) * 32 + quad * 8];
#pragma unroll
    for (int mi = 0; mi < 2; mi++)
#pragma unroll
      for (int ni = 0; ni < 2; ni++)
        acc[mi][ni] = mfma16x16x32(af[mi], bfr[ni], acc[mi][ni]);
    cur ^= 1;
  }

  float* po = pout + (long)blockIdx.z * (1024 * 1024);
#pragma unroll
  for (int ni = 0; ni < 2; ni++) {
    const int col = n0 + wn + ni * 16 + ln;
#pragma unroll
    for (int mi = 0; mi < 2; mi++)
#pragma unroll
      for (int r = 0; r < 4; r++) {
        const int row = m0 + wm + mi * 16 + quad * 4 + r;
        po[(long)row * 1024 + col] = acc[mi][ni][r];
      }
  }
}

// ---------------------------------------------------------------------------
// Reduce 4 fp32 partials -> bf16 Wf^T. 1M elems, float4-vectorized.
// ---------------------------------------------------------------------------
__global__ __launch_bounds__(256)
void reduce_wf(const float* __restrict__ p, bf16* __restrict__ wft) {
  const long i = ((long)blockIdx.x * 256 + threadIdx.x) * 4;
  float4 a = *(const float4*)(p + i);
  float4 b = *(const float4*)(p + i + 1048576);
  float4 c = *(const float4*)(p + i + 2097152);
  float4 d = *(const float4*)(p + i + 3145728);
  ushort4 pk;
  pk.x = b2u((a.x + b.x) + (c.x + d.x));
  pk.y = b2u((a.y + b.y) + (c.y + d.y));
  pk.z = b2u((a.z + b.z) + (c.z + d.z));
  pk.w = b2u((a.w + b.w) + (c.w + d.w));
  *(ushort4*)((ushort*)wft + i) = pk;
}

// ---------------------------------------------------------------------------
// Flash attention v5: LDS-staged K/V + defer-max (T13) + deferred-l.
// grid 1024 blocks (16 q-blocks x 64 bh, XCD-clustered). 4 waves x 32 q-rows.
// NO loop unroll: round-9 A/B showed unroll-2 pushes the per-XCD working set
// past L2 capacity (FETCH +5MB, WRITE +10MB, dur +10.5us). Keep rolled.
// q,k: [B,H,S,64]; vt: [B,H,64,S]. Out: [B,S,D] bf16.
// ---------------------------------------------------------------------------
__global__ __launch_bounds__(256, 4)
void attn_kernel(const bf16* __restrict__ q, const bf16* __restrict__ k,
                 const bf16* __restrict__ vt, bf16* __restrict__ o) {
  __shared__ bf16 Ks[2][64 * 64];
  __shared__ bf16 Vs[2][64 * 64];
  const int t = threadIdx.x, wave = t >> 6, lane = t & 63;
  const int quad = lane >> 4, ln = lane & 15;
  const int id = blockIdx.x;
  const int bh = ((id & 7) << 3) | ((id >> 3) >> 4);  // 8 consecutive bh/XCD
  const int qb = (id >> 3) & 15;
  const int q0 = qb * 128 + wave * 32;
  const long base = (long)bh * (2048 * 64);

  // Q as B-operand frags (register-resident)
  v8s qf[2][2];
#pragma unroll
  for (int mi = 0; mi < 2; mi++)
#pragma unroll
    for (int kc = 0; kc < 2; kc++)
      qf[mi][kc] = *(const v8s*)(q + base + (long)(q0 + mi * 16 + ln) * 64 +
                                 kc * 32 + quad * 8);

  v4f accO[2][4];  // [mi][nh]: O^T tile, col=ln (q-row), row=quad*4+r (hd)
  float m2[2], lp[2];  // lp: PER-LANE partial denominator
#pragma unroll
  for (int mi = 0; mi < 2; mi++) {
#pragma unroll
    for (int nh = 0; nh < 4; nh++) accO[mi][nh] = v4f{0.f, 0.f, 0.f, 0.f};
    m2[mi] = -1e30f;
    lp[mi] = 0.f;
  }

  // staging offsets (loop-invariant). Linear LDS off; inverse-swizzled src.
  const int o0 = t * 16, o1 = t * 16 + 4096;
  const int ks0 = o0 ^ (((o0 >> 7) & 7) << 4);
  const int ks1 = o1 ^ (((o1 >> 7) & 7) << 4);
  const int h0 = o0 >> 7, h1 = o1 >> 7;
  const int vs0 = h0 * 4096 + ((o0 ^ ((h0 & 7) << 4)) & 127);
  const int vs1 = h1 * 4096 + ((o1 ^ ((h1 & 7) << 4)) & 127);
  const char* kgb = (const char*)(k + base);
  const char* vgb = (const char*)(vt + base);

  // prologue: stage tile 0 into buffer 0
  {
    char* kl = (char*)&Ks[0][0];
    char* vl = (char*)&Vs[0][0];
    load_lds16(kgb + ks0, kl + o0);
    load_lds16(kgb + ks1, kl + o1);
    load_lds16(vgb + vs0, vl + o0);
    load_lds16(vgb + vs1, vl + o1);
  }

  for (int it = 0; it < 32; ++it) {
    const int bf = it & 1;
    __syncthreads();  // staging(bf) drained; all waves done reading bf^1
    if (it + 1 < 32) {
      const char* kg = kgb + (long)(it + 1) * (64 * 128);  // 8KB per K-tile
      const char* vg = vgb + (long)(it + 1) * 128;         // 64 keys * 2B
      char* kl = (char*)&Ks[bf ^ 1][0];
      char* vl = (char*)&Vs[bf ^ 1][0];
      load_lds16(kg + ks0, kl + o0);
      load_lds16(kg + ks1, kl + o1);
      load_lds16(vg + vs0, vl + o0);
      load_lds16(vg + vs1, vl + o1);
    }
    const char* Kb = (const char*)&Ks[bf][0];
    const char* Vb = (const char*)&Vs[bf][0];

    // S^T tiles: st[mi][ni] at lane: key = ni*16+quad*4+r, qrow = mi*16+ln
    v4f st[2][4];
    __builtin_amdgcn_s_setprio(1);
#pragma unroll
    for (int ni = 0; ni < 4; ni++) {
      const int r = ni * 16 + ln;
      const int sw = (r & 7) << 4;
      v8s k0 = *(const v8s*)(Kb + ((r * 128 + quad * 16) ^ sw));
      v8s k1 = *(const v8s*)(Kb + ((r * 128 + 64 + quad * 16) ^ sw));
#pragma unroll
      for (int mi = 0; mi < 2; mi++) {
        v4f z = v4f{0.f, 0.f, 0.f, 0.f};
        z = mfma16x16x32(k0, qf[mi][0], z);
        st[mi][ni] = mfma16x16x32(k1, qf[mi][1], z);
      }
    }
    __builtin_amdgcn_s_setprio(0);

    // online softmax (defer-max, per-lane l) -> P^T packed into x16 B-frags
    v4s pf[2][4];
#pragma unroll
    for (int mi = 0; mi < 2; mi++) {
      float a0 = fmaxf(fmaxf(st[mi][0][0], st[mi][0][1]),
                       fmaxf(st[mi][0][2], st[mi][0][3]));
      float a1 = fmaxf(fmaxf(st[mi][1][0], st[mi][1][1]),
                       fmaxf(st[mi][1][2], st[mi][1][3]));
      float a2 = fmaxf(fmaxf(st[mi][2][0], st[mi][2][1]),
                       fmaxf(st[mi][2][2], st[mi][2][3]));
      float a3 = fmaxf(fmaxf(st[mi][3][0], st[mi][3][1]),
                       fmaxf(st[mi][3][2], st[mi][3][3]));
      float mx = fmaxf(fmaxf(a0, a1), fmaxf(a2, a3));
      mx = fmaxf(mx, __shfl_xor(mx, 16));
      mx = fmaxf(mx, __shfl_xor(mx, 32));
      const float mo = m2[mi];
      if (!__all(mx <= mo + 8.0f)) {  // T13: rescale only when max grew >THR
        const float mn = fmaxf(mo, mx);
        const float al = fexp2(mo - mn);
        m2[mi] = mn;
        lp[mi] *= al;
#pragma unroll
        for (int nh = 0; nh < 4; nh++)
#pragma unroll
          for (int r = 0; r < 4; r++) accO[mi][nh][r] *= al;
      }
      const float mu = m2[mi];
      float rs = 0.f;
#pragma unroll
      for (int ni = 0; ni < 4; ni++) {
        v4s p4;
#pragma unroll
        for (int r = 0; r < 4; r++) {
          float p = fexp2(st[mi][ni][r] - mu);
          rs += p;
          p4[r] = (short)b2u(p);
        }
        pf[mi][ni] = p4;
      }
      lp[mi] += rs;  // per-lane partial; cross-quad reduce in epilogue
    }

    // O^T += V^T . P^T  (A = V^T frag from LDS, B = P^T frag)
    __builtin_amdgcn_s_setprio(1);
#pragma unroll
    for (int nh = 0; nh < 4; nh++) {
      const int row = nh * 16 + ln;
      const int sw = (row & 7) << 4;
#pragma unroll
      for (int ni = 0; ni < 4; ni++) {
        v4s vv = *(const v4s*)(Vb + ((row * 128 + ni * 32 + quad * 8) ^ sw));
#pragma unroll
        for (int mi = 0; mi < 2; mi++)
          accO[mi][nh] = mfma16x16x16(vv, pf[mi][ni], accO[mi][nh]);
      }
    }
    __builtin_amdgcn_s_setprio(0);
  }

  // epilogue: reduce per-lane l across quads, then write O
  const int b_ = bh >> 4, h_ = bh & 15;
#pragma unroll
  for (int mi = 0; mi < 2; mi++) {
    float lr = lp[mi];
    lr += __shfl_xor(lr, 16);
    lr += __shfl_xor(lr, 32);
    const float inv = 1.0f / lr;
    const int s = q0 + mi * 16 + ln;
#pragma unroll
    for (int nh = 0; nh < 4; nh++) {
      ushort4 pk;
      pk.x = b2u(finz(accO[mi][nh][0] * inv, 5000.f));
      pk.y = b2u(finz(accO[mi][nh][1] * inv, 5000.f));
      pk.z = b2u(finz(accO[mi][nh][2] * inv, 5000.f));
      pk.w = b2u(finz(accO[mi][nh][3] * inv, 5000.f));
      *(ushort4*)((ushort*)o + ((long)(b_ * 2048 + s)) * 1024 + h_ * 64 +
                  nh * 16 + quad * 4) = pk;
    }
  }
}

// ---------------------------------------------------------------------------
extern "C" void kernel_launch(void* const* d_in, const int* in_sizes, int n_in,
                              void* d_out, int out_size, void* d_ws,
                              size_t ws_size, hipStream_t stream) {
  const float* x   = (const float*)d_in[0];
  const float* Wq  = (const float*)d_in[1];
  const float* bq  = (const float*)d_in[2];
  const float* Wk  = (const float*)d_in[3];
  const float* bk  = (const float*)d_in[4];
  const float* Wv  = (const float*)d_in[5];
  const float* bv  = (const float*)d_in[6];
  const float* Wo  = (const float*)d_in[7];
  const float* bo  = (const float*)d_in[8];
  const float* W1  = (const float*)d_in[9];
  const float* b1  = (const float*)d_in[10];
  const float* W2  = (const float*)d_in[11];
  const float* b2  = (const float*)d_in[12];
  const float* g1  = (const float*)d_in[13];
  const float* be1 = (const float*)d_in[14];
  const float* g2  = (const float*)d_in[15];
  const float* be2 = (const float*)d_in[16];
  float* out = (float*)d_out;

  const size_t MB = 1024 * 1024;
  if (ws_size < 104 * MB) return;
  char* W = (char*)d_ws;
  bf16* wqt = (bf16*)(W + 0 * MB);
  bf16* wkt = (bf16*)(W + 2 * MB);
  bf16* wvt = (bf16*)(W + 4 * MB);
  bf16* wot = (bf16*)(W + 6 * MB);
  bf16* h   = (bf16*)(W + 8 * MB);    // LN1 out; later LN2 out (16MB, 8-24)
  bf16* qb  = (bf16*)(W + 24 * MB);   // dead after attn
  bf16* kb  = (bf16*)(W + 40 * MB);   // dead after attn
  bf16* vb  = (bf16*)(W + 56 * MB);   // v TRANSPOSED; dead after attn
  bf16* ao  = (bf16*)(W + 72 * MB);   // dead after Wo-gemm
  bf16* x1  = (bf16*)(W + 88 * MB);   // live to end (16MB, 88-104)
  bf16* w1b = (bf16*)(W + 24 * MB);   // after attn (qb slot): W1 bf16 8MB, 24-32
  bf16* w2t = (bf16*)(W + 32 * MB);   // W2^T bf16 [1024][4096] 8MB, 32-40
  bf16* wft = (bf16*)(W + 40 * MB);   // Wf^T bf16 [1024][1024] 2MB, 40-42
  float* bfb = (float*)(W + 44 * MB); // fused FFN bias [1024] fp32
  float* wfp = (float*)(W + 56 * MB); // Wf split-K partials [4][1024][1024] 16MB
                                      //   56-72 (vb slot, dead after attn)

  repack_qkv<<<4096, 256, 0, stream>>>(Wq, wqt);
  repack_qkv<<<4096, 256, 0, stream>>>(Wk, wkt);
  repack_qkv<<<4096, 256, 0, stream>>>(Wv, wvt);
  transpose_f2b<<<dim3(32, 32), 256, 0, stream>>>(Wo, wot, 1024, 1024);

  // 1) h = LN1(x)
  ln_kernel<float><<<8192, 256, 0, stream>>>(x, g1, be1, h);
  // 2) q,k,v = h @ Wqkv + b  (q scaled; q,k -> [B,H,S,64]; v -> [B,H,64,S])
  gemm_bt<3><<<dim3(24, 64), 256, 0, stream>>>(h, wqt, bq, bk, bv, nullptr,
                                               qb, kb, vb, 8192, 3072, 1024);
  // 3) flash attention -> ao [B,S,D]
  attn_kernel<<<dim3(1024), 256, 0, stream>>>(qb, kb, vb, ao);
  // 4) x1 = x + ao @ Wo + bo  (128x64 tiles -> 1024 blocks, 4/CU)
  gemm_bt12864<1><<<dim3(16, 64), 256, 0, stream>>>(ao, wot, bo, x, x1,
                                                    8192, 1024, 1024);
  // --- FFN reparameterization: gelu((h2@W1+b1)@W2+b2) == gelu(h2@Wf + bf).
  cast_f2b<<<4096, 256, 0, stream>>>(W1, w1b);   // 4M elems = 4096 blocks
  transpose_f2b<<<dim3(32, 128), 256, 0, stream>>>(W2, w2t, 4096, 1024);
  gemm_wf_splitk<<<dim3(16, 16, 4), 256, 0, stream>>>(w2t, w1b, wfp);
  reduce_wf<<<1024, 256, 0, stream>>>(wfp, wft);
  ffn_bias<<<1024, 256, 0, stream>>>(b1, W2, b2, bfb);
  // 5) h2 = LN2(x1)
  ln_kernel<bf16><<<8192, 256, 0, stream>>>(x1, g2, be2, h);
  // 6) out = x1 + gelu(h2 @ Wf + bf)  (128x64 tiles -> 1024 blocks)
  gemm_bt12864<2><<<dim3(16, 64), 256, 0, stream>>>(h, wft, bfb, x1, out,
                                                    8192, 1024, 1024);
}